// Round 10
// baseline (2455.179 us; speedup 1.0000x reference)
//
#include <hip/hip_runtime.h>

typedef unsigned int uint;
typedef unsigned short ushort;

__device__ __forceinline__ float bfl(uint u){ return __uint_as_float(u << 16); }
__device__ __forceinline__ float bfh(uint u){ return __uint_as_float(u & 0xFFFF0000u); }
__device__ __forceinline__ uint f2bfbits(float f){
    uint b = __float_as_uint(f);
    return (b + 0x7FFFu + ((b >> 16) & 1u)) >> 16;
}
__device__ __forceinline__ uint packbf2(float a, float b){
    return f2bfbits(a) | (f2bfbits(b) << 16);
}
__device__ __forceinline__ int smap(int4 m, int s){
    return (s == 0) ? m.x : (s == 1) ? m.y : (s == 2) ? m.z : m.w;
}
__device__ __forceinline__ int2 ldnt(const int2* p){
    long long v = __builtin_nontemporal_load((const long long*)p);
    int2 r; r.x = (int)(v & 0xFFFFFFFFll); r.y = (int)(v >> 32); return r;
}

#define CH 6144
#define SBSHIFT 7
#define SBROWS 128
#define HISTP 784
#define SBUF_CAP 5120
#define PGRID 2048

// accumulate one (edge,gather) pair into s,q
#define ACCBP(sx,sy,qx,qy,cv,u) { \
    float v_ = __int_as_float((cv).y); \
    float xx_ = bfl(u), yy_ = bfh(u); \
    sx = fmaf(v_, xx_, sx); sy = fmaf(v_, yy_, sy); \
    qx = fmaf(v_ * xx_, xx_, qx); qy = fmaf(v_ * yy_, yy_, qy); }

#define ACCS(ax,ay,cv,u) { \
    float v_ = __int_as_float((cv).y); \
    ax = fmaf(v_, bfl(u), ax); ay = fmaf(v_, bfh(u), ay); }

// ---------------- dense part ----------------

#define BM 64
#define BK 32
__global__ __launch_bounds__(256) void gemm_kernel(const float* __restrict__ x,
                                                   const float* __restrict__ Wa,
                                                   const float* __restrict__ Wb,
                                                   float* __restrict__ AB, int N) {
    __shared__ float xsT[BK][BM + 4];
    __shared__ float wsm[BK][256];
    int t = threadIdx.x;
    int rowbase = blockIdx.x * BM;
    int tx = t & 15, ty = t >> 4;
    float acc[4][16];
    #pragma unroll
    for (int i = 0; i < 4; i++)
        #pragma unroll
        for (int j = 0; j < 16; j++) acc[i][j] = 0.f;

    for (int k0 = 0; k0 < 256; k0 += BK) {
        {
            int r = t & 63;
            int koff = (t >> 6) * 8;
            int gr = rowbase + r; if (gr >= N) gr = N - 1;
            const float* src = x + (size_t)gr * 256 + k0 + koff;
            float4 u0 = *(const float4*)(src);
            float4 u1 = *(const float4*)(src + 4);
            xsT[koff + 0][r] = u0.x; xsT[koff + 1][r] = u0.y;
            xsT[koff + 2][r] = u0.z; xsT[koff + 3][r] = u0.w;
            xsT[koff + 4][r] = u1.x; xsT[koff + 5][r] = u1.y;
            xsT[koff + 6][r] = u1.z; xsT[koff + 7][r] = u1.w;
        }
        {
            #pragma unroll
            for (int i = 0; i < 8; i++) {
                int f = t + i * 256;
                int rr = f >> 6, c4 = f & 63;
                const float* src = (c4 < 32) ? &Wa[(size_t)(k0 + rr) * 128 + c4 * 4]
                                             : &Wb[(size_t)(k0 + rr) * 128 + (c4 - 32) * 4];
                *(float4*)&wsm[rr][c4 * 4] = *(const float4*)src;
            }
        }
        __syncthreads();
        #pragma unroll
        for (int kk = 0; kk < BK; ++kk) {
            float4 a = *(const float4*)&xsT[kk][ty * 4];
            float av[4] = {a.x, a.y, a.z, a.w};
            float bv[16];
            #pragma unroll
            for (int q = 0; q < 4; q++)
                *(float4*)&bv[q * 4] = *(const float4*)&wsm[kk][q * 64 + tx * 4];
            #pragma unroll
            for (int i = 0; i < 4; i++)
                #pragma unroll
                for (int j = 0; j < 16; j++)
                    acc[i][j] = fmaf(av[i], bv[j], acc[i][j]);
        }
        __syncthreads();
    }
    #pragma unroll
    for (int i = 0; i < 4; i++) {
        int gr = rowbase + ty * 4 + i;
        if (gr < N) {
            #pragma unroll
            for (int q = 0; q < 4; q++) {
                float4 o = {acc[i][q*4], acc[i][q*4+1], acc[i][q*4+2], acc[i][q*4+3]};
                *(float4*)&AB[(size_t)gr * 256 + q * 64 + tx * 4] = o;
            }
        }
    }
}

// attention: Pb[n] packed bf16 [N][128]
__global__ __launch_bounds__(256) void attn_kernel(const float* __restrict__ AB,
        const float* __restrict__ w1, const float* __restrict__ b1,
        const float* __restrict__ w2, uint* __restrict__ Pb, int N) {
    __shared__ float w1s[128 * 32];
    __shared__ float b1s[32], w2s[32];
    __shared__ float aS[4][128], alS[4][128];
    int t = threadIdx.x;
    #pragma unroll
    for (int i = 0; i < 16; i++) w1s[t + i * 256] = w1[t + i * 256];
    if (t < 32) { b1s[t] = b1[t]; w2s[t] = w2[t]; }

    int w = t >> 6, lane = t & 63;
    int node = blockIdx.x * 4 + w;
    bool active = node < N;
    int nclamp = active ? node : (N - 1);
    float2 a = *(const float2*)(AB + (size_t)nclamp * 256 + lane * 2);
    float2 b = *(const float2*)(AB + (size_t)nclamp * 256 + 128 + lane * 2);
    float2 al;
    al.x = a.x + 0.5f * (a.x * a.x - a.x * b.x);
    al.y = a.y + 0.5f * (a.y * a.y - a.y * b.y);
    aS[w][lane * 2] = a.x;   aS[w][lane * 2 + 1] = a.y;
    alS[w][lane * 2] = al.x; alS[w][lane * 2 + 1] = al.y;
    __syncthreads();

    int j = lane & 31;
    const float* src = (lane < 32) ? aS[w] : alS[w];
    float acc = b1s[j];
    #pragma unroll 8
    for (int d = 0; d < 128; ++d) acc = fmaf(src[d], w1s[d * 32 + j], acc);
    float h = tanhf(acc);
    float prod = h * w2s[j];
    #pragma unroll
    for (int off = 1; off < 32; off <<= 1) prod += __shfl_xor(prod, off);
    float eo = __shfl_xor(prod, 32);
    float e0 = (lane < 32) ? prod : eo;
    float e1 = (lane < 32) ? eo : prod;
    float m = fmaxf(e0, e1);
    float p0 = expf(e0 - m), p1 = expf(e1 - m);
    float inv = 1.0f / (p0 + p1);
    float at0 = p0 * inv, at1 = p1 * inv;
    if (active) {
        float px = at0 * a.x + at1 * al.x;
        float py = at0 * a.y + at1 * al.y;
        Pb[(size_t)node * 64 + lane] = packbf2(px, py);
    }
}

// ---------------- CSR build (bucket-major reorder, zero global atomics) ----------------

__device__ __forceinline__ void block_scan1024(int* a, int t, int* wsum) {
    int lane = t & 63, wid = t >> 6;
    int c0 = a[t * 4], c1 = a[t * 4 + 1], c2 = a[t * 4 + 2], c3 = a[t * 4 + 3];
    int tsum = c0 + c1 + c2 + c3, incl = tsum;
    #pragma unroll
    for (int off = 1; off < 64; off <<= 1) {
        int y = __shfl_up(incl, off);
        if (lane >= off) incl += y;
    }
    if (lane == 63) wsum[wid] = incl;
    __syncthreads();
    int wb = 0;
    #pragma unroll
    for (int w = 0; w < 4; w++) if (w < wid) wb += wsum[w];
    int excl = wb + incl - tsum;
    a[t * 4] = excl; a[t * 4 + 1] = excl + c0;
    a[t * 4 + 2] = excl + c0 + c1; a[t * 4 + 3] = excl + c0 + c1 + c2;
    __syncthreads();
}

__global__ __launch_bounds__(256) void count_chunk(const int* __restrict__ rows, int4 map,
        int* __restrict__ lenTab, int* __restrict__ gtot, int NSB, int nchunks, int E) {
    __shared__ int hist[HISTP];
    int c = blockIdx.x, s = blockIdx.y, t = threadIdx.x;
    size_t sb = (size_t)smap(map, s) * E;
    int e0 = c * CH, e1 = e0 + CH; if (e1 > E) e1 = E;
    for (int i = t; i < HISTP; i += 256) hist[i] = 0;
    __syncthreads();
    for (int e = e0 + t; e < e1; e += 256)
        atomicAdd(&hist[(uint)rows[sb + e] >> SBSHIFT], 1);
    __syncthreads();
    for (int b = t; b < NSB; b += 256) {
        int l = hist[b];
        lenTab[((size_t)s * NSB + b) * nchunks + c] = l;
        if (l) atomicAdd(&gtot[s * NSB + b], l);
    }
}

__global__ __launch_bounds__(256) void bucket_scanex(const int* __restrict__ gtot,
        int* __restrict__ bbase, int NSB) {
    __shared__ int a[1024];
    __shared__ int wsum[4];
    int s = blockIdx.x, t = threadIdx.x;
    #pragma unroll
    for (int k = 0; k < 4; k++) {
        int i = t + k * 256;
        a[i] = (i < NSB) ? gtot[s * NSB + i] : 0;
    }
    __syncthreads();
    block_scan1024(a, t, wsum);
    #pragma unroll
    for (int k = 0; k < 4; k++) {
        int i = t + k * 256;
        if (i <= NSB) bbase[s * (NSB + 1) + i] = a[i];
    }
}

__global__ __launch_bounds__(64) void pos_scan(const int* __restrict__ lenTab,
        const int* __restrict__ bbase, int* __restrict__ segPos, int NSB, int nchunks) {
    int b = blockIdx.x, s = blockIdx.y, lane = threadIdx.x;
    const int* lt = lenTab + ((size_t)s * NSB + b) * nchunks;
    int* sp = segPos + ((size_t)s * NSB + b) * nchunks;
    int run = bbase[s * (NSB + 1) + b];
    for (int c0 = 0; c0 < nchunks; c0 += 64) {
        int c = c0 + lane;
        int v = (c < nchunks) ? lt[c] : 0;
        int incl = v;
        #pragma unroll
        for (int off = 1; off < 64; off <<= 1) {
            int y = __shfl_up(incl, off);
            if (lane >= off) incl += y;
        }
        if (c < nchunks) sp[c] = run + incl - v;
        run += __shfl(incl, 63);
    }
}

__global__ __launch_bounds__(256) void place_chunk(const int* __restrict__ rows,
        const int* __restrict__ cols, const float* __restrict__ vals, int4 map,
        const int* __restrict__ segPos, int2* __restrict__ stage2,
        int NSB, int nchunks, int E) {
    __shared__ int2 sbuf[CH];
    __shared__ ushort bmap[CH];
    __shared__ int cur[1024];
    __shared__ int off[1024];
    __shared__ int spos[HISTP];
    __shared__ int wsum[4];
    int c = blockIdx.x, s = blockIdx.y, t = threadIdx.x;
    size_t sb = (size_t)smap(map, s) * E;
    int e0 = c * CH, e1 = e0 + CH; if (e1 > E) e1 = E;
    int csz = e1 - e0;
    #pragma unroll
    for (int k = 0; k < 4; k++) cur[t + k * 256] = 0;
    __syncthreads();
    for (int e = e0 + t; e < e1; e += 256)
        atomicAdd(&cur[(uint)rows[sb + e] >> SBSHIFT], 1);
    __syncthreads();
    block_scan1024(cur, t, wsum);
    #pragma unroll
    for (int k = 0; k < 4; k++) { int i = t + k * 256; off[i] = cur[i]; }
    for (int b = t; b < NSB; b += 256)
        spos[b] = segPos[((size_t)s * NSB + b) * nchunks + c];
    __syncthreads();
    for (int e = e0 + t; e < e1; e += 256) {
        int r = rows[sb + e];
        int b = (uint)r >> SBSHIFT;
        int pos = atomicAdd(&cur[b], 1);
        uint cw = (uint)cols[sb + e] | ((uint)(r & (SBROWS - 1)) << 20);
        sbuf[pos] = make_int2((int)cw, __float_as_int(vals[sb + e]));
        bmap[pos] = (ushort)b;
    }
    __syncthreads();
    int2* dst = stage2 + (size_t)s * E;
    for (int i = t; i < csz; i += 256) {
        int b = bmap[i];
        dst[spos[b] + (i - off[b])] = sbuf[i];
    }
}

__global__ __launch_bounds__(256) void fill_bucket(const int2* __restrict__ stage2,
        const int* __restrict__ bbase, int* __restrict__ rp, int2* __restrict__ pk,
        int NSB, int N, int E) {
    __shared__ int2 sbuf[SBUF_CAP];
    __shared__ int cur[128];
    __shared__ int loc[132];
    __shared__ int wsum2[2];
    int b = blockIdx.x, s = blockIdx.y, t = threadIdx.x;
    int lane = t & 63, wid = t >> 6;
    int rowbase = b << SBSHIFT;
    int nrows = N - rowbase; if (nrows > SBROWS) nrows = SBROWS;
    size_t sb = (size_t)s * E;
    int beg = bbase[s * (NSB + 1) + b];
    int end = bbase[s * (NSB + 1) + b + 1];
    int tot = end - beg;
    if (t < 128) cur[t] = 0;
    __syncthreads();
    for (int i = beg + t; i < end; i += 256)
        atomicAdd(&cur[((uint)stage2[sb + i].x) >> 20], 1);
    __syncthreads();
    int v = 0, incl = 0;
    if (t < 128) {
        v = cur[t]; incl = v;
        #pragma unroll
        for (int off = 1; off < 64; off <<= 1) {
            int y = __shfl_up(incl, off);
            if (lane >= off) incl += y;
        }
        if (lane == 63) wsum2[wid] = incl;
    }
    __syncthreads();
    if (t < 128) {
        int excl = incl - v + ((wid == 1) ? wsum2[0] : 0);
        loc[t] = excl; cur[t] = excl;
        if (t < nrows) rp[(size_t)s * (N + 1) + rowbase + t] = beg + excl;
    }
    if (t == 0) loc[128] = tot;
    if (b == 0 && t == 0) rp[(size_t)s * (N + 1) + N] = E;
    __syncthreads();
    for (int i = beg + t; i < end; i += 256) {
        int2 u = stage2[sb + i];
        int lr = ((uint)u.x) >> 20;
        int pos = atomicAdd(&cur[lr], 1);
        int2 w = make_int2(u.x & 0xFFFFF, u.y);
        if (pos < SBUF_CAP) sbuf[pos] = w; else pk[sb + beg + pos] = w;
    }
    __syncthreads();
    for (int r = wid; r < nrows; r += 4) {
        int rb = loc[r], re = loc[r + 1];
        int deg = re - rb;
        if (deg < 2 || deg > 64 || re > SBUF_CAP) continue;
        int key = 0x7FFFFFFF, val = 0;
        if (lane < deg) { int2 u = sbuf[rb + lane]; key = u.x; val = u.y; }
        #pragma unroll
        for (int k = 2; k <= 64; k <<= 1) {
            #pragma unroll
            for (int j = k >> 1; j > 0; j >>= 1) {
                int okey = __shfl_xor(key, j);
                int oval = __shfl_xor(val, j);
                bool up = ((lane & k) == 0);
                bool lower = ((lane & j) == 0);
                bool keepmin = (lower == up);
                bool take = keepmin ? (okey < key) : (okey > key);
                if (take) { key = okey; val = oval; }
            }
        }
        if (lane < deg) sbuf[rb + lane] = make_int2(key, val);
    }
    __syncthreads();
    int lim = (tot < SBUF_CAP) ? tot : SBUF_CAP;
    for (int i = t; i < lim; i += 256)
        __builtin_nontemporal_store(*(const long long*)&sbuf[i], (long long*)&pk[sb + beg + i]);
}

// ---------------- fused SpMM kernels (persistent, sorted-walk, interleaved streams) ----------------

__device__ __forceinline__ void row_gather_sum(const int2* __restrict__ pk,
        int e, int end, const uint* __restrict__ Xb, int lane,
        float& ax, float& ay) {
    for (; e + 2 <= end; e += 2) {
        int2 c0 = ldnt(&pk[e]); int2 c1 = ldnt(&pk[e + 1]);
        uint u0 = Xb[(c0.x << 6) + lane]; uint u1 = Xb[(c1.x << 6) + lane];
        ACCS(ax, ay, c0, u0); ACCS(ax, ay, c1, u1);
    }
    if (e < end) {
        int2 c0 = ldnt(&pk[e]);
        uint u0 = Xb[(c0.x << 6) + lane];
        ACCS(ax, ay, c0, u0);
    }
}

__device__ __forceinline__ void row_gather_bp(const int2* __restrict__ pk,
        int e, int end, const uint* __restrict__ Xb, int lane,
        float& sx, float& sy, float& qx, float& qy) {
    for (; e + 2 <= end; e += 2) {
        int2 c0 = ldnt(&pk[e]); int2 c1 = ldnt(&pk[e + 1]);
        uint u0 = Xb[(c0.x << 6) + lane]; uint u1 = Xb[(c1.x << 6) + lane];
        ACCBP(sx, sy, qx, qy, c0, u0); ACCBP(sx, sy, qx, qy, c1, u1);
    }
    if (e < end) {
        int2 c0 = ldnt(&pk[e]);
        uint u0 = Xb[(c0.x << 6) + lane];
        ACCBP(sx, sy, qx, qy, c0, u0);
    }
}

// 4 CSRs over the same Xb; writes t1 = bp(s0)-bp(s1), t2 = bp(s2)-bp(s3)
__global__ __launch_bounds__(256) void spmm_bp4(const int* __restrict__ rp1,
        const int2* __restrict__ pk1, const int* __restrict__ rp2,
        const int2* __restrict__ pk2, const int* __restrict__ rp3,
        const int2* __restrict__ pk3, const int* __restrict__ rp4,
        const int2* __restrict__ pk4, const uint* __restrict__ Xb,
        uint* __restrict__ out1, uint* __restrict__ out2, int N) {
    int w = threadIdx.x >> 6, lane = threadIdx.x & 63;
    int stride = gridDim.x * 4;
    for (int row = blockIdx.x * 4 + w; row < N; row += stride) {
        float s1x=0.f,s1y=0.f,q1x=0.f,q1y=0.f;
        float s2x=0.f,s2y=0.f,q2x=0.f,q2y=0.f;
        float s3x=0.f,s3y=0.f,q3x=0.f,q3y=0.f;
        float s4x=0.f,s4y=0.f,q4x=0.f,q4y=0.f;
        int e1 = rp1[row], n1 = rp1[row + 1];
        int e2 = rp2[row], n2 = rp2[row + 1];
        int e3 = rp3[row], n3 = rp3[row + 1];
        int e4 = rp4[row], n4 = rp4[row + 1];
        // steady state: 8 independent gathers in flight, column walks lockstep
        while (e1 + 2 <= n1 && e2 + 2 <= n2 && e3 + 2 <= n3 && e4 + 2 <= n4) {
            int2 a0 = ldnt(&pk1[e1]); int2 a1 = ldnt(&pk1[e1 + 1]);
            int2 b0 = ldnt(&pk2[e2]); int2 b1 = ldnt(&pk2[e2 + 1]);
            int2 c0 = ldnt(&pk3[e3]); int2 c1 = ldnt(&pk3[e3 + 1]);
            int2 d0 = ldnt(&pk4[e4]); int2 d1 = ldnt(&pk4[e4 + 1]);
            uint ua0 = Xb[(a0.x << 6) + lane]; uint ua1 = Xb[(a1.x << 6) + lane];
            uint ub0 = Xb[(b0.x << 6) + lane]; uint ub1 = Xb[(b1.x << 6) + lane];
            uint uc0 = Xb[(c0.x << 6) + lane]; uint uc1 = Xb[(c1.x << 6) + lane];
            uint ud0 = Xb[(d0.x << 6) + lane]; uint ud1 = Xb[(d1.x << 6) + lane];
            ACCBP(s1x,s1y,q1x,q1y,a0,ua0); ACCBP(s1x,s1y,q1x,q1y,a1,ua1);
            ACCBP(s2x,s2y,q2x,q2y,b0,ub0); ACCBP(s2x,s2y,q2x,q2y,b1,ub1);
            ACCBP(s3x,s3y,q3x,q3y,c0,uc0); ACCBP(s3x,s3y,q3x,q3y,c1,uc1);
            ACCBP(s4x,s4y,q4x,q4y,d0,ud0); ACCBP(s4x,s4y,q4x,q4y,d1,ud1);
            e1 += 2; e2 += 2; e3 += 2; e4 += 2;
        }
        row_gather_bp(pk1, e1, n1, Xb, lane, s1x, s1y, q1x, q1y);
        row_gather_bp(pk2, e2, n2, Xb, lane, s2x, s2y, q2x, q2y);
        row_gather_bp(pk3, e3, n3, Xb, lane, s3x, s3y, q3x, q3y);
        row_gather_bp(pk4, e4, n4, Xb, lane, s4x, s4y, q4x, q4y);
        float t1x = 0.5f * ((s1x * s1x - q1x) - (s2x * s2x - q2x));
        float t1y = 0.5f * ((s1y * s1y - q1y) - (s2y * s2y - q2y));
        float t2xv = 0.5f * ((s3x * s3x - q3x) - (s4x * s4x - q4x));
        float t2yv = 0.5f * ((s3y * s3y - q3y) - (s4y * s4y - q4y));
        size_t o = ((size_t)row << 6) + lane;
        out1[o] = packbf2(t1x, t1y);
        out2[o] = packbf2(t2xv, t2yv);
    }
}

__global__ __launch_bounds__(256) void spmm_out(const int* __restrict__ rp0,
        const int2* __restrict__ pk0, const int* __restrict__ rp5,
        const int2* __restrict__ pk5, const int* __restrict__ rp6,
        const int2* __restrict__ pk6, const uint* __restrict__ Pb,
        const uint* __restrict__ t1b, const uint* __restrict__ t2b,
        float* __restrict__ out, int N) {
    int w = threadIdx.x >> 6, lane = threadIdx.x & 63;
    int stride = gridDim.x * 4;
    for (int row = blockIdx.x * 4 + w; row < N; row += stride) {
        float a0x = 0.f, a0y = 0.f, a5x = 0.f, a5y = 0.f, a6x = 0.f, a6y = 0.f;
        int e0 = rp0[row], n0 = rp0[row + 1];
        int e5 = rp5[row], n5 = rp5[row + 1];
        int e6 = rp6[row], n6 = rp6[row + 1];
        while (e0 + 2 <= n0 && e5 + 2 <= n5 && e6 + 2 <= n6) {
            int2 c00 = ldnt(&pk0[e0]); int2 c01 = ldnt(&pk0[e0 + 1]);
            int2 c50 = ldnt(&pk5[e5]); int2 c51 = ldnt(&pk5[e5 + 1]);
            int2 c60 = ldnt(&pk6[e6]); int2 c61 = ldnt(&pk6[e6 + 1]);
            uint u00 = Pb[(c00.x << 6) + lane];  uint u01 = Pb[(c01.x << 6) + lane];
            uint u50 = t1b[(c50.x << 6) + lane]; uint u51 = t1b[(c51.x << 6) + lane];
            uint u60 = t2b[(c60.x << 6) + lane]; uint u61 = t2b[(c61.x << 6) + lane];
            ACCS(a0x, a0y, c00, u00); ACCS(a0x, a0y, c01, u01);
            ACCS(a5x, a5y, c50, u50); ACCS(a5x, a5y, c51, u51);
            ACCS(a6x, a6y, c60, u60); ACCS(a6x, a6y, c61, u61);
            e0 += 2; e5 += 2; e6 += 2;
        }
        row_gather_sum(pk0, e0, n0, Pb,  lane, a0x, a0y);
        row_gather_sum(pk5, e5, n5, t1b, lane, a5x, a5y);
        row_gather_sum(pk6, e6, n6, t2b, lane, a6x, a6y);
        float rx = fmaxf(0.5f * a0x + 0.25f * a5x + 0.25f * a6x, 0.f);
        float ry = fmaxf(0.5f * a0y + 0.25f * a5y + 0.25f * a6y, 0.f);
        *(float2*)(out + ((size_t)row << 7) + (lane << 1)) = make_float2(rx, ry);
    }
}

// ---------------- launch ----------------

extern "C" void kernel_launch(void* const* d_in, const int* in_sizes, int n_in,
                              void* d_out, int out_size, void* d_ws, size_t ws_size,
                              hipStream_t stream) {
    (void)n_in; (void)out_size; (void)ws_size;
    const float* x   = (const float*)d_in[0];
    const float* Wa  = (const float*)d_in[1];
    const float* Wb  = (const float*)d_in[2];
    const float* w1  = (const float*)d_in[4];
    const float* b1  = (const float*)d_in[5];
    const float* w2  = (const float*)d_in[6];
    const int* rows  = (const int*)d_in[7];
    const int* cols  = (const int*)d_in[8];
    const float* vals = (const float*)d_in[9];
    float* out = (float*)d_out;

    const int N = in_sizes[0] / 256;
    const int E = in_sizes[7] / 7;
    const int NSB = (N + SBROWS - 1) >> SBSHIFT;
    const int nchunks = (E + CH - 1) / CH;

    uint* Pb  = (uint*)d_ws;
    uint* t1b = Pb + (size_t)N * 64;
    uint* t2b = t1b + (size_t)N * 64;
    int2* pk  = (int2*)(t2b + (size_t)N * 64);
    size_t regionFloats = (size_t)N * 256;
    if ((size_t)8 * E > regionFloats) regionFloats = (size_t)8 * E;
    int2* stage2 = pk + (size_t)4 * E;
    float* AB    = (float*)stage2;
    int* rp      = (int*)((float*)stage2 + regionFloats);
    int* lenTab  = rp + 4 * (size_t)(N + 1);
    int* segPos  = lenTab + (size_t)4 * NSB * nchunks;
    int* gtot    = segPos + (size_t)4 * NSB * nchunks;
    int* bbase   = gtot + (size_t)4 * NSB;

    dim3 b256(256);
    int sgrid = (N + 3) / 4;
    int pgrid = PGRID; if (pgrid > sgrid) pgrid = sgrid;

    gemm_kernel<<<(N + BM - 1) / BM, b256, 0, stream>>>(x, Wa, Wb, AB, N);
    attn_kernel<<<sgrid, b256, 0, stream>>>(AB, w1, b1, w2, Pb, N);

    auto build = [&](int4 map, int nsup) {
        hipMemsetAsync(gtot, 0, (size_t)nsup * NSB * sizeof(int), stream);
        count_chunk<<<dim3(nchunks, nsup), b256, 0, stream>>>(rows, map, lenTab, gtot,
                                                              NSB, nchunks, E);
        bucket_scanex<<<nsup, b256, 0, stream>>>(gtot, bbase, NSB);
        pos_scan<<<dim3(NSB, nsup), dim3(64), 0, stream>>>(lenTab, bbase, segPos, NSB, nchunks);
        place_chunk<<<dim3(nchunks, nsup), b256, 0, stream>>>(rows, cols, vals, map,
                                                              segPos, stage2, NSB, nchunks, E);
        fill_bucket<<<dim3(NSB, nsup), b256, 0, stream>>>(stage2, bbase, rp, pk, NSB, N, E);
    };

    const int NP1 = N + 1;

    // group A: slots {1,3,2,4} -> t1 = bp(1)-bp(3), t2 = bp(2)-bp(4) in ONE pass
    build(make_int4(1, 3, 2, 4), 4);
    spmm_bp4<<<pgrid, b256, 0, stream>>>(rp + 0 * NP1, pk + 0 * (size_t)E,
                                         rp + 1 * NP1, pk + 1 * (size_t)E,
                                         rp + 2 * NP1, pk + 2 * (size_t)E,
                                         rp + 3 * NP1, pk + 3 * (size_t)E,
                                         Pb, t1b, t2b, N);

    // group B: slots {0,5,6}
    build(make_int4(0, 5, 6, 6), 3);
    spmm_out<<<pgrid, b256, 0, stream>>>(rp + 0 * NP1, pk + 0 * (size_t)E,
                                         rp + 1 * NP1, pk + 1 * (size_t)E,
                                         rp + 2 * NP1, pk + 2 * (size_t)E,
                                         Pb, t1b, t2b, out, N);
}

// Round 11
// 2195.168 us; speedup vs baseline: 1.1184x; 1.1184x over previous
//
#include <hip/hip_runtime.h>

typedef unsigned int uint;
typedef unsigned short ushort;

__device__ __forceinline__ float bfl(uint u){ return __uint_as_float(u << 16); }
__device__ __forceinline__ float bfh(uint u){ return __uint_as_float(u & 0xFFFF0000u); }
__device__ __forceinline__ uint f2bfbits(float f){
    uint b = __float_as_uint(f);
    return (b + 0x7FFFu + ((b >> 16) & 1u)) >> 16;
}
__device__ __forceinline__ uint packbf2(float a, float b){
    return f2bfbits(a) | (f2bfbits(b) << 16);
}
__device__ __forceinline__ int smap(int4 m, int s){
    return (s == 0) ? m.x : (s == 1) ? m.y : (s == 2) ? m.z : m.w;
}
__device__ __forceinline__ int2 ldnt(const int2* p){
    long long v = __builtin_nontemporal_load((const long long*)p);
    int2 r; r.x = (int)(v & 0xFFFFFFFFll); r.y = (int)(v >> 32); return r;
}

#define CH 6144
#define SBSHIFT 7
#define SBROWS 128
#define HISTP 784
#define SBUF_CAP 5120
#define CACHE_PT 20      // 20*256 = 5120 = SBUF_CAP exactly
#define PGRID 2048

// ---------------- dense part ----------------

#define BM 64
#define BK 32
__global__ __launch_bounds__(256) void gemm_kernel(const float* __restrict__ x,
                                                   const float* __restrict__ Wa,
                                                   const float* __restrict__ Wb,
                                                   float* __restrict__ AB, int N) {
    __shared__ float xsT[BK][BM + 4];
    __shared__ float wsm[BK][256];
    int t = threadIdx.x;
    int rowbase = blockIdx.x * BM;
    int tx = t & 15, ty = t >> 4;
    float acc[4][16];
    #pragma unroll
    for (int i = 0; i < 4; i++)
        #pragma unroll
        for (int j = 0; j < 16; j++) acc[i][j] = 0.f;

    for (int k0 = 0; k0 < 256; k0 += BK) {
        {
            int r = t & 63;
            int koff = (t >> 6) * 8;
            int gr = rowbase + r; if (gr >= N) gr = N - 1;
            const float* src = x + (size_t)gr * 256 + k0 + koff;
            float4 u0 = *(const float4*)(src);
            float4 u1 = *(const float4*)(src + 4);
            xsT[koff + 0][r] = u0.x; xsT[koff + 1][r] = u0.y;
            xsT[koff + 2][r] = u0.z; xsT[koff + 3][r] = u0.w;
            xsT[koff + 4][r] = u1.x; xsT[koff + 5][r] = u1.y;
            xsT[koff + 6][r] = u1.z; xsT[koff + 7][r] = u1.w;
        }
        {
            #pragma unroll
            for (int i = 0; i < 8; i++) {
                int f = t + i * 256;
                int rr = f >> 6, c4 = f & 63;
                const float* src = (c4 < 32) ? &Wa[(size_t)(k0 + rr) * 128 + c4 * 4]
                                             : &Wb[(size_t)(k0 + rr) * 128 + (c4 - 32) * 4];
                *(float4*)&wsm[rr][c4 * 4] = *(const float4*)src;
            }
        }
        __syncthreads();
        #pragma unroll
        for (int kk = 0; kk < BK; ++kk) {
            float4 a = *(const float4*)&xsT[kk][ty * 4];
            float av[4] = {a.x, a.y, a.z, a.w};
            float bv[16];
            #pragma unroll
            for (int q = 0; q < 4; q++)
                *(float4*)&bv[q * 4] = *(const float4*)&wsm[kk][q * 64 + tx * 4];
            #pragma unroll
            for (int i = 0; i < 4; i++)
                #pragma unroll
                for (int j = 0; j < 16; j++)
                    acc[i][j] = fmaf(av[i], bv[j], acc[i][j]);
        }
        __syncthreads();
    }
    #pragma unroll
    for (int i = 0; i < 4; i++) {
        int gr = rowbase + ty * 4 + i;
        if (gr < N) {
            #pragma unroll
            for (int q = 0; q < 4; q++) {
                float4 o = {acc[i][q*4], acc[i][q*4+1], acc[i][q*4+2], acc[i][q*4+3]};
                *(float4*)&AB[(size_t)gr * 256 + q * 64 + tx * 4] = o;
            }
        }
    }
}

// attention: Pb[n] packed bf16 [N][128]
__global__ __launch_bounds__(256) void attn_kernel(const float* __restrict__ AB,
        const float* __restrict__ w1, const float* __restrict__ b1,
        const float* __restrict__ w2, uint* __restrict__ Pb, int N) {
    __shared__ float w1s[128 * 32];
    __shared__ float b1s[32], w2s[32];
    __shared__ float aS[4][128], alS[4][128];
    int t = threadIdx.x;
    #pragma unroll
    for (int i = 0; i < 16; i++) w1s[t + i * 256] = w1[t + i * 256];
    if (t < 32) { b1s[t] = b1[t]; w2s[t] = w2[t]; }

    int w = t >> 6, lane = t & 63;
    int node = blockIdx.x * 4 + w;
    bool active = node < N;
    int nclamp = active ? node : (N - 1);
    float2 a = *(const float2*)(AB + (size_t)nclamp * 256 + lane * 2);
    float2 b = *(const float2*)(AB + (size_t)nclamp * 256 + 128 + lane * 2);
    float2 al;
    al.x = a.x + 0.5f * (a.x * a.x - a.x * b.x);
    al.y = a.y + 0.5f * (a.y * a.y - a.y * b.y);
    aS[w][lane * 2] = a.x;   aS[w][lane * 2 + 1] = a.y;
    alS[w][lane * 2] = al.x; alS[w][lane * 2 + 1] = al.y;
    __syncthreads();

    int j = lane & 31;
    const float* src = (lane < 32) ? aS[w] : alS[w];
    float acc = b1s[j];
    #pragma unroll 8
    for (int d = 0; d < 128; ++d) acc = fmaf(src[d], w1s[d * 32 + j], acc);
    float h = tanhf(acc);
    float prod = h * w2s[j];
    #pragma unroll
    for (int off = 1; off < 32; off <<= 1) prod += __shfl_xor(prod, off);
    float eo = __shfl_xor(prod, 32);
    float e0 = (lane < 32) ? prod : eo;
    float e1 = (lane < 32) ? eo : prod;
    float m = fmaxf(e0, e1);
    float p0 = expf(e0 - m), p1 = expf(e1 - m);
    float inv = 1.0f / (p0 + p1);
    float at0 = p0 * inv, at1 = p1 * inv;
    if (active) {
        float px = at0 * a.x + at1 * al.x;
        float py = at0 * a.y + at1 * al.y;
        Pb[(size_t)node * 64 + lane] = packbf2(px, py);
    }
}

// ---------------- CSR build (bucket-major reorder, zero global atomics) ----------------

__device__ __forceinline__ void block_scan1024(int* a, int t, int* wsum) {
    int lane = t & 63, wid = t >> 6;
    int c0 = a[t * 4], c1 = a[t * 4 + 1], c2 = a[t * 4 + 2], c3 = a[t * 4 + 3];
    int tsum = c0 + c1 + c2 + c3, incl = tsum;
    #pragma unroll
    for (int off = 1; off < 64; off <<= 1) {
        int y = __shfl_up(incl, off);
        if (lane >= off) incl += y;
    }
    if (lane == 63) wsum[wid] = incl;
    __syncthreads();
    int wb = 0;
    #pragma unroll
    for (int w = 0; w < 4; w++) if (w < wid) wb += wsum[w];
    int excl = wb + incl - tsum;
    a[t * 4] = excl; a[t * 4 + 1] = excl + c0;
    a[t * 4 + 2] = excl + c0 + c1; a[t * 4 + 3] = excl + c0 + c1 + c2;
    __syncthreads();
}

__global__ __launch_bounds__(256) void count_chunk(const int* __restrict__ rows, int4 map,
        int* __restrict__ lenTab, int* __restrict__ gtot, int NSB, int nchunks, int E) {
    __shared__ int hist[HISTP];
    int c = blockIdx.x, s = blockIdx.y, t = threadIdx.x;
    size_t sb = (size_t)smap(map, s) * E;
    int e0 = c * CH, e1 = e0 + CH; if (e1 > E) e1 = E;
    for (int i = t; i < HISTP; i += 256) hist[i] = 0;
    __syncthreads();
    for (int e = e0 + t; e < e1; e += 256)
        atomicAdd(&hist[(uint)rows[sb + e] >> SBSHIFT], 1);
    __syncthreads();
    for (int b = t; b < NSB; b += 256) {
        int l = hist[b];
        lenTab[((size_t)s * NSB + b) * nchunks + c] = l;
        if (l) atomicAdd(&gtot[s * NSB + b], l);
    }
}

__global__ __launch_bounds__(256) void bucket_scanex(const int* __restrict__ gtot,
        int* __restrict__ bbase, int NSB) {
    __shared__ int a[1024];
    __shared__ int wsum[4];
    int s = blockIdx.x, t = threadIdx.x;
    #pragma unroll
    for (int k = 0; k < 4; k++) {
        int i = t + k * 256;
        a[i] = (i < NSB) ? gtot[s * NSB + i] : 0;
    }
    __syncthreads();
    block_scan1024(a, t, wsum);
    #pragma unroll
    for (int k = 0; k < 4; k++) {
        int i = t + k * 256;
        if (i <= NSB) bbase[s * (NSB + 1) + i] = a[i];
    }
}

__global__ __launch_bounds__(64) void pos_scan(const int* __restrict__ lenTab,
        const int* __restrict__ bbase, int* __restrict__ segPos, int NSB, int nchunks) {
    int b = blockIdx.x, s = blockIdx.y, lane = threadIdx.x;
    const int* lt = lenTab + ((size_t)s * NSB + b) * nchunks;
    int* sp = segPos + ((size_t)s * NSB + b) * nchunks;
    int run = bbase[s * (NSB + 1) + b];
    for (int c0 = 0; c0 < nchunks; c0 += 64) {
        int c = c0 + lane;
        int v = (c < nchunks) ? lt[c] : 0;
        int incl = v;
        #pragma unroll
        for (int off = 1; off < 64; off <<= 1) {
            int y = __shfl_up(incl, off);
            if (lane >= off) incl += y;
        }
        if (c < nchunks) sp[c] = run + incl - v;
        run += __shfl(incl, 63);
    }
}

__global__ __launch_bounds__(256) void place_chunk(const int* __restrict__ rows,
        const int* __restrict__ cols, const float* __restrict__ vals, int4 map,
        const int* __restrict__ segPos, int2* __restrict__ stage2,
        int NSB, int nchunks, int E) {
    __shared__ int2 sbuf[CH];
    __shared__ ushort bmap[CH];
    __shared__ int cur[1024];
    __shared__ int off[1024];
    __shared__ int spos[HISTP];
    __shared__ int wsum[4];
    int c = blockIdx.x, s = blockIdx.y, t = threadIdx.x;
    size_t sb = (size_t)smap(map, s) * E;
    int e0 = c * CH, e1 = e0 + CH; if (e1 > E) e1 = E;
    int csz = e1 - e0;
    #pragma unroll
    for (int k = 0; k < 4; k++) cur[t + k * 256] = 0;
    __syncthreads();
    for (int e = e0 + t; e < e1; e += 256)
        atomicAdd(&cur[(uint)rows[sb + e] >> SBSHIFT], 1);
    __syncthreads();
    block_scan1024(cur, t, wsum);
    #pragma unroll
    for (int k = 0; k < 4; k++) { int i = t + k * 256; off[i] = cur[i]; }
    for (int b = t; b < NSB; b += 256)
        spos[b] = segPos[((size_t)s * NSB + b) * nchunks + c];
    __syncthreads();
    for (int e = e0 + t; e < e1; e += 256) {
        int r = rows[sb + e];
        int b = (uint)r >> SBSHIFT;
        int pos = atomicAdd(&cur[b], 1);
        uint cw = (uint)cols[sb + e] | ((uint)(r & (SBROWS - 1)) << 20);
        sbuf[pos] = make_int2((int)cw, __float_as_int(vals[sb + e]));
        bmap[pos] = (ushort)b;
    }
    __syncthreads();
    int2* dst = stage2 + (size_t)s * E;
    for (int i = t; i < csz; i += 256) {
        int b = bmap[i];
        dst[spos[b] + (i - off[b])] = sbuf[i];
    }
}

// bucket contiguous in stage2: ONE global read (register-cached), LDS place,
// per-row col-sort, single linear pk write.
__global__ __launch_bounds__(256) void fill_bucket(const int2* __restrict__ stage2,
        const int* __restrict__ bbase, int* __restrict__ rp, int2* __restrict__ pk,
        int NSB, int N, int E) {
    __shared__ int2 sbuf[SBUF_CAP];
    __shared__ int cur[128];
    __shared__ int loc[132];
    __shared__ int wsum2[2];
    int b = blockIdx.x, s = blockIdx.y, t = threadIdx.x;
    int lane = t & 63, wid = t >> 6;
    int rowbase = b << SBSHIFT;
    int nrows = N - rowbase; if (nrows > SBROWS) nrows = SBROWS;
    size_t sb = (size_t)s * E;
    int beg = bbase[s * (NSB + 1) + b];
    int end = bbase[s * (NSB + 1) + b + 1];
    int tot = end - beg;
    if (t < 128) cur[t] = 0;
    __syncthreads();
    // pass 1: single contiguous read; cache edges in registers (static indices)
    int2 myE[CACHE_PT];
    #pragma unroll
    for (int k = 0; k < CACHE_PT; k++) {
        int idx = t + k * 256;
        if (idx < tot) {
            int2 u = stage2[sb + beg + idx];
            myE[k] = u;
            atomicAdd(&cur[((uint)u.x) >> 20], 1);
        }
    }
    for (int idx = t + CACHE_PT * 256; idx < tot; idx += 256) {   // overflow (rare)
        int2 u = stage2[sb + beg + idx];
        atomicAdd(&cur[((uint)u.x) >> 20], 1);
    }
    __syncthreads();
    // 128-wide scan -> local offsets + rp
    int v = 0, incl = 0;
    if (t < 128) {
        v = cur[t]; incl = v;
        #pragma unroll
        for (int off = 1; off < 64; off <<= 1) {
            int y = __shfl_up(incl, off);
            if (lane >= off) incl += y;
        }
        if (lane == 63) wsum2[wid] = incl;
    }
    __syncthreads();
    if (t < 128) {
        int excl = incl - v + ((wid == 1) ? wsum2[0] : 0);
        loc[t] = excl; cur[t] = excl;
        if (t < nrows) rp[(size_t)s * (N + 1) + rowbase + t] = beg + excl;
    }
    if (t == 0) loc[128] = tot;
    if (b == 0 && t == 0) rp[(size_t)s * (N + 1) + N] = E;
    __syncthreads();
    // pass 2: place from registers into LDS by row
    #pragma unroll
    for (int k = 0; k < CACHE_PT; k++) {
        int idx = t + k * 256;
        if (idx < tot) {
            int2 u = myE[k];
            int lr = ((uint)u.x) >> 20;
            int pos = atomicAdd(&cur[lr], 1);
            int2 w = make_int2(u.x & 0xFFFFF, u.y);
            if (pos < SBUF_CAP) sbuf[pos] = w; else pk[sb + beg + pos] = w;
        }
    }
    for (int idx = t + CACHE_PT * 256; idx < tot; idx += 256) {   // overflow (rare)
        int2 u = stage2[sb + beg + idx];
        int lr = ((uint)u.x) >> 20;
        int pos = atomicAdd(&cur[lr], 1);
        int2 w = make_int2(u.x & 0xFFFFF, u.y);
        if (pos < SBUF_CAP) sbuf[pos] = w; else pk[sb + beg + pos] = w;
    }
    __syncthreads();
    // per-row bitonic col-sort in LDS (wave per row)
    for (int r = wid; r < nrows; r += 4) {
        int rb = loc[r], re = loc[r + 1];
        int deg = re - rb;
        if (deg < 2 || deg > 64 || re > SBUF_CAP) continue;
        int key = 0x7FFFFFFF, val = 0;
        if (lane < deg) { int2 u = sbuf[rb + lane]; key = u.x; val = u.y; }
        #pragma unroll
        for (int k = 2; k <= 64; k <<= 1) {
            #pragma unroll
            for (int j = k >> 1; j > 0; j >>= 1) {
                int okey = __shfl_xor(key, j);
                int oval = __shfl_xor(val, j);
                bool up = ((lane & k) == 0);
                bool lower = ((lane & j) == 0);
                bool keepmin = (lower == up);
                bool take = keepmin ? (okey < key) : (okey > key);
                if (take) { key = okey; val = oval; }
            }
        }
        if (lane < deg) sbuf[rb + lane] = make_int2(key, val);
    }
    __syncthreads();
    int lim = (tot < SBUF_CAP) ? tot : SBUF_CAP;
    for (int i = t; i < lim; i += 256)
        __builtin_nontemporal_store(*(const long long*)&sbuf[i], (long long*)&pk[sb + beg + i]);
}

// ---------------- fused SpMM kernels (persistent, sorted-walk, MLP=4) ----------------

__device__ __forceinline__ void row_gather_sum(const int2* __restrict__ pk,
        int e, int end, const uint* __restrict__ Xb, int lane,
        float& ax, float& ay) {
    for (; e + 4 <= end; e += 4) {
        int2 c0 = ldnt(&pk[e]);     int2 c1 = ldnt(&pk[e + 1]);
        int2 c2 = ldnt(&pk[e + 2]); int2 c3 = ldnt(&pk[e + 3]);
        uint u0 = Xb[(c0.x << 6) + lane]; uint u1 = Xb[(c1.x << 6) + lane];
        uint u2 = Xb[(c2.x << 6) + lane]; uint u3 = Xb[(c3.x << 6) + lane];
        float v0 = __int_as_float(c0.y), v1 = __int_as_float(c1.y);
        float v2 = __int_as_float(c2.y), v3 = __int_as_float(c3.y);
        ax = fmaf(v0, bfl(u0), ax); ay = fmaf(v0, bfh(u0), ay);
        ax = fmaf(v1, bfl(u1), ax); ay = fmaf(v1, bfh(u1), ay);
        ax = fmaf(v2, bfl(u2), ax); ay = fmaf(v2, bfh(u2), ay);
        ax = fmaf(v3, bfl(u3), ax); ay = fmaf(v3, bfh(u3), ay);
    }
    for (; e < end; ++e) {
        int2 c0 = ldnt(&pk[e]);
        uint u0 = Xb[(c0.x << 6) + lane];
        float v0 = __int_as_float(c0.y);
        ax = fmaf(v0, bfl(u0), ax); ay = fmaf(v0, bfh(u0), ay);
    }
}

__device__ __forceinline__ void row_gather_bp(const int2* __restrict__ pk,
        int e, int end, const uint* __restrict__ Xb, int lane,
        float& sx, float& sy, float& qx, float& qy) {
    for (; e + 4 <= end; e += 4) {
        int2 c0 = ldnt(&pk[e]);     int2 c1 = ldnt(&pk[e + 1]);
        int2 c2 = ldnt(&pk[e + 2]); int2 c3 = ldnt(&pk[e + 3]);
        uint u0 = Xb[(c0.x << 6) + lane]; uint u1 = Xb[(c1.x << 6) + lane];
        uint u2 = Xb[(c2.x << 6) + lane]; uint u3 = Xb[(c3.x << 6) + lane];
        float v0 = __int_as_float(c0.y), v1 = __int_as_float(c1.y);
        float v2 = __int_as_float(c2.y), v3 = __int_as_float(c3.y);
        float x0 = bfl(u0), y0 = bfh(u0), x1 = bfl(u1), y1 = bfh(u1);
        float x2 = bfl(u2), y2 = bfh(u2), x3 = bfl(u3), y3 = bfh(u3);
        sx = fmaf(v0, x0, sx); sy = fmaf(v0, y0, sy);
        qx = fmaf(v0 * x0, x0, qx); qy = fmaf(v0 * y0, y0, qy);
        sx = fmaf(v1, x1, sx); sy = fmaf(v1, y1, sy);
        qx = fmaf(v1 * x1, x1, qx); qy = fmaf(v1 * y1, y1, qy);
        sx = fmaf(v2, x2, sx); sy = fmaf(v2, y2, sy);
        qx = fmaf(v2 * x2, x2, qx); qy = fmaf(v2 * y2, y2, qy);
        sx = fmaf(v3, x3, sx); sy = fmaf(v3, y3, sy);
        qx = fmaf(v3 * x3, x3, qx); qy = fmaf(v3 * y3, y3, qy);
    }
    for (; e < end; ++e) {
        int2 c0 = ldnt(&pk[e]);
        uint u0 = Xb[(c0.x << 6) + lane];
        float v0 = __int_as_float(c0.y);
        float x0 = bfl(u0), y0 = bfh(u0);
        sx = fmaf(v0, x0, sx); sy = fmaf(v0, y0, sy);
        qx = fmaf(v0 * x0, x0, qx); qy = fmaf(v0 * y0, y0, qy);
    }
}

__global__ __launch_bounds__(256) void spmm_bp2(const int* __restrict__ rpA,
        const int2* __restrict__ pkA, const int* __restrict__ rpB,
        const int2* __restrict__ pkB, const uint* __restrict__ Xb,
        uint* __restrict__ outb, int N) {
    int w = threadIdx.x >> 6, lane = threadIdx.x & 63;
    int stride = gridDim.x * 4;
    for (int row = blockIdx.x * 4 + w; row < N; row += stride) {
        float sax = 0.f, say = 0.f, qax = 0.f, qay = 0.f;
        float sbx = 0.f, sby = 0.f, qbx = 0.f, qby = 0.f;
        row_gather_bp(pkA, rpA[row], rpA[row + 1], Xb, lane, sax, say, qax, qay);
        row_gather_bp(pkB, rpB[row], rpB[row + 1], Xb, lane, sbx, sby, qbx, qby);
        float tx = 0.5f * ((sax * sax - qax) - (sbx * sbx - qbx));
        float ty = 0.5f * ((say * say - qay) - (sby * sby - qby));
        outb[((size_t)row << 6) + lane] = packbf2(tx, ty);
    }
}

__global__ __launch_bounds__(256) void spmm_out(const int* __restrict__ rp0,
        const int2* __restrict__ pk0, const int* __restrict__ rp5,
        const int2* __restrict__ pk5, const int* __restrict__ rp6,
        const int2* __restrict__ pk6, const uint* __restrict__ Pb,
        const uint* __restrict__ t1b, const uint* __restrict__ t2b,
        float* __restrict__ out, int N) {
    int w = threadIdx.x >> 6, lane = threadIdx.x & 63;
    int stride = gridDim.x * 4;
    for (int row = blockIdx.x * 4 + w; row < N; row += stride) {
        float a0x = 0.f, a0y = 0.f, a5x = 0.f, a5y = 0.f, a6x = 0.f, a6y = 0.f;
        row_gather_sum(pk0, rp0[row], rp0[row + 1], Pb,  lane, a0x, a0y);
        row_gather_sum(pk5, rp5[row], rp5[row + 1], t1b, lane, a5x, a5y);
        row_gather_sum(pk6, rp6[row], rp6[row + 1], t2b, lane, a6x, a6y);
        float rx = fmaxf(0.5f * a0x + 0.25f * a5x + 0.25f * a6x, 0.f);
        float ry = fmaxf(0.5f * a0y + 0.25f * a5y + 0.25f * a6y, 0.f);
        *(float2*)(out + ((size_t)row << 7) + (lane << 1)) = make_float2(rx, ry);
    }
}

// ---------------- launch ----------------

extern "C" void kernel_launch(void* const* d_in, const int* in_sizes, int n_in,
                              void* d_out, int out_size, void* d_ws, size_t ws_size,
                              hipStream_t stream) {
    (void)n_in; (void)out_size; (void)ws_size;
    const float* x   = (const float*)d_in[0];
    const float* Wa  = (const float*)d_in[1];
    const float* Wb  = (const float*)d_in[2];
    const float* w1  = (const float*)d_in[4];
    const float* b1  = (const float*)d_in[5];
    const float* w2  = (const float*)d_in[6];
    const int* rows  = (const int*)d_in[7];
    const int* cols  = (const int*)d_in[8];
    const float* vals = (const float*)d_in[9];
    float* out = (float*)d_out;

    const int N = in_sizes[0] / 256;
    const int E = in_sizes[7] / 7;
    const int NSB = (N + SBROWS - 1) >> SBSHIFT;
    const int nchunks = (E + CH - 1) / CH;

    uint* Pb  = (uint*)d_ws;
    uint* t1b = Pb + (size_t)N * 64;
    uint* t2b = t1b + (size_t)N * 64;
    int2* pk  = (int2*)(t2b + (size_t)N * 64);
    size_t regionFloats = (size_t)N * 256;
    if ((size_t)8 * E > regionFloats) regionFloats = (size_t)8 * E;
    int2* stage2 = pk + (size_t)4 * E;
    float* AB    = (float*)stage2;
    int* rp      = (int*)((float*)stage2 + regionFloats);
    int* lenTab  = rp + 4 * (size_t)(N + 1);
    int* segPos  = lenTab + (size_t)4 * NSB * nchunks;
    int* gtot    = segPos + (size_t)4 * NSB * nchunks;
    int* bbase   = gtot + (size_t)4 * NSB;

    dim3 b256(256);
    int sgrid = (N + 3) / 4;
    int pgrid = PGRID; if (pgrid > sgrid) pgrid = sgrid;

    gemm_kernel<<<(N + BM - 1) / BM, b256, 0, stream>>>(x, Wa, Wb, AB, N);
    attn_kernel<<<sgrid, b256, 0, stream>>>(AB, w1, b1, w2, Pb, N);

    auto build = [&](int4 map, int nsup) {
        hipMemsetAsync(gtot, 0, (size_t)nsup * NSB * sizeof(int), stream);
        count_chunk<<<dim3(nchunks, nsup), b256, 0, stream>>>(rows, map, lenTab, gtot,
                                                              NSB, nchunks, E);
        bucket_scanex<<<nsup, b256, 0, stream>>>(gtot, bbase, NSB);
        pos_scan<<<dim3(NSB, nsup), dim3(64), 0, stream>>>(lenTab, bbase, segPos, NSB, nchunks);
        place_chunk<<<dim3(nchunks, nsup), b256, 0, stream>>>(rows, cols, vals, map,
                                                              segPos, stage2, NSB, nchunks, E);
        fill_bucket<<<dim3(NSB, nsup), b256, 0, stream>>>(stage2, bbase, rp, pk, NSB, N, E);
    };

    const int NP1 = N + 1;

    // group A: slots {1,3,2,4}
    build(make_int4(1, 3, 2, 4), 4);
    spmm_bp2<<<pgrid, b256, 0, stream>>>(rp + 0 * NP1, pk + 0 * (size_t)E,
                                         rp + 1 * NP1, pk + 1 * (size_t)E, Pb, t1b, N);
    spmm_bp2<<<pgrid, b256, 0, stream>>>(rp + 2 * NP1, pk + 2 * (size_t)E,
                                         rp + 3 * NP1, pk + 3 * (size_t)E, Pb, t2b, N);

    // group B: slots {0,5,6}
    build(make_int4(0, 5, 6, 6), 3);
    spmm_out<<<pgrid, b256, 0, stream>>>(rp + 0 * NP1, pk + 0 * (size_t)E,
                                         rp + 1 * NP1, pk + 1 * (size_t)E,
                                         rp + 2 * NP1, pk + 2 * (size_t)E,
                                         Pb, t1b, t2b, out, N);
}

// Round 12
// 2160.514 us; speedup vs baseline: 1.1364x; 1.0160x over previous
//
#include <hip/hip_runtime.h>

typedef unsigned int uint;
typedef unsigned short ushort;

__device__ __forceinline__ float bfl(uint u){ return __uint_as_float(u << 16); }
__device__ __forceinline__ float bfh(uint u){ return __uint_as_float(u & 0xFFFF0000u); }
__device__ __forceinline__ uint f2bfbits(float f){
    uint b = __float_as_uint(f);
    return (b + 0x7FFFu + ((b >> 16) & 1u)) >> 16;
}
__device__ __forceinline__ uint packbf2(float a, float b){
    return f2bfbits(a) | (f2bfbits(b) << 16);
}
__device__ __forceinline__ int smap8(int4 lo, int4 hi, int s){
    int4 m = (s < 4) ? lo : hi;
    int k = s & 3;
    return (k == 0) ? m.x : (k == 1) ? m.y : (k == 2) ? m.z : m.w;
}
__device__ __forceinline__ int2 ldnt(const int2* p){
    long long v = __builtin_nontemporal_load((const long long*)p);
    int2 r; r.x = (int)(v & 0xFFFFFFFFll); r.y = (int)(v >> 32); return r;
}
// bijective XCD-contiguous chunk swizzle (blocks with same bid%8 -> contiguous range)
__device__ __forceinline__ int xcd_swz(int bid, int n){
    int q = n >> 3, r = n & 7;
    int x = bid & 7, i = bid >> 3;
    return (x < r) ? (x * (q + 1) + i) : (r * (q + 1) + (x - r) * q + i);
}

#define CH 6144
#define SBSHIFT 7
#define SBROWS 128
#define HISTP 784
#define SBUF_CAP 5120
#define CACHE_PT 20
#define PGRID 2048

// ---------------- dense part ----------------

#define BM 64
#define BK 32
__global__ __launch_bounds__(256) void gemm_kernel(const float* __restrict__ x,
                                                   const float* __restrict__ Wa,
                                                   const float* __restrict__ Wb,
                                                   float* __restrict__ AB, int N) {
    __shared__ float xsT[BK][BM + 4];
    __shared__ float wsm[BK][256];
    int t = threadIdx.x;
    int rowbase = blockIdx.x * BM;
    int tx = t & 15, ty = t >> 4;
    float acc[4][16];
    #pragma unroll
    for (int i = 0; i < 4; i++)
        #pragma unroll
        for (int j = 0; j < 16; j++) acc[i][j] = 0.f;

    for (int k0 = 0; k0 < 256; k0 += BK) {
        {
            int r = t & 63;
            int koff = (t >> 6) * 8;
            int gr = rowbase + r; if (gr >= N) gr = N - 1;
            const float* src = x + (size_t)gr * 256 + k0 + koff;
            float4 u0 = *(const float4*)(src);
            float4 u1 = *(const float4*)(src + 4);
            xsT[koff + 0][r] = u0.x; xsT[koff + 1][r] = u0.y;
            xsT[koff + 2][r] = u0.z; xsT[koff + 3][r] = u0.w;
            xsT[koff + 4][r] = u1.x; xsT[koff + 5][r] = u1.y;
            xsT[koff + 6][r] = u1.z; xsT[koff + 7][r] = u1.w;
        }
        {
            #pragma unroll
            for (int i = 0; i < 8; i++) {
                int f = t + i * 256;
                int rr = f >> 6, c4 = f & 63;
                const float* src = (c4 < 32) ? &Wa[(size_t)(k0 + rr) * 128 + c4 * 4]
                                             : &Wb[(size_t)(k0 + rr) * 128 + (c4 - 32) * 4];
                *(float4*)&wsm[rr][c4 * 4] = *(const float4*)src;
            }
        }
        __syncthreads();
        #pragma unroll
        for (int kk = 0; kk < BK; ++kk) {
            float4 a = *(const float4*)&xsT[kk][ty * 4];
            float av[4] = {a.x, a.y, a.z, a.w};
            float bv[16];
            #pragma unroll
            for (int q = 0; q < 4; q++)
                *(float4*)&bv[q * 4] = *(const float4*)&wsm[kk][q * 64 + tx * 4];
            #pragma unroll
            for (int i = 0; i < 4; i++)
                #pragma unroll
                for (int j = 0; j < 16; j++)
                    acc[i][j] = fmaf(av[i], bv[j], acc[i][j]);
        }
        __syncthreads();
    }
    #pragma unroll
    for (int i = 0; i < 4; i++) {
        int gr = rowbase + ty * 4 + i;
        if (gr < N) {
            #pragma unroll
            for (int q = 0; q < 4; q++) {
                float4 o = {acc[i][q*4], acc[i][q*4+1], acc[i][q*4+2], acc[i][q*4+3]};
                *(float4*)&AB[(size_t)gr * 256 + q * 64 + tx * 4] = o;
            }
        }
    }
}

// attention: Pb[n] packed bf16 [N][128]
__global__ __launch_bounds__(256) void attn_kernel(const float* __restrict__ AB,
        const float* __restrict__ w1, const float* __restrict__ b1,
        const float* __restrict__ w2, uint* __restrict__ Pb, int N) {
    __shared__ float w1s[128 * 32];
    __shared__ float b1s[32], w2s[32];
    __shared__ float aS[4][128], alS[4][128];
    int t = threadIdx.x;
    #pragma unroll
    for (int i = 0; i < 16; i++) w1s[t + i * 256] = w1[t + i * 256];
    if (t < 32) { b1s[t] = b1[t]; w2s[t] = w2[t]; }

    int w = t >> 6, lane = t & 63;
    int node = blockIdx.x * 4 + w;
    bool active = node < N;
    int nclamp = active ? node : (N - 1);
    float2 a = *(const float2*)(AB + (size_t)nclamp * 256 + lane * 2);
    float2 b = *(const float2*)(AB + (size_t)nclamp * 256 + 128 + lane * 2);
    float2 al;
    al.x = a.x + 0.5f * (a.x * a.x - a.x * b.x);
    al.y = a.y + 0.5f * (a.y * a.y - a.y * b.y);
    aS[w][lane * 2] = a.x;   aS[w][lane * 2 + 1] = a.y;
    alS[w][lane * 2] = al.x; alS[w][lane * 2 + 1] = al.y;
    __syncthreads();

    int j = lane & 31;
    const float* src = (lane < 32) ? aS[w] : alS[w];
    float acc = b1s[j];
    #pragma unroll 8
    for (int d = 0; d < 128; ++d) acc = fmaf(src[d], w1s[d * 32 + j], acc);
    float h = tanhf(acc);
    float prod = h * w2s[j];
    #pragma unroll
    for (int off = 1; off < 32; off <<= 1) prod += __shfl_xor(prod, off);
    float eo = __shfl_xor(prod, 32);
    float e0 = (lane < 32) ? prod : eo;
    float e1 = (lane < 32) ? eo : prod;
    float m = fmaxf(e0, e1);
    float p0 = expf(e0 - m), p1 = expf(e1 - m);
    float inv = 1.0f / (p0 + p1);
    float at0 = p0 * inv, at1 = p1 * inv;
    if (active) {
        float px = at0 * a.x + at1 * al.x;
        float py = at0 * a.y + at1 * al.y;
        Pb[(size_t)node * 64 + lane] = packbf2(px, py);
    }
}

// ---------------- CSR build (bucket-major reorder, zero global atomics) ----------------

__device__ __forceinline__ void block_scan1024(int* a, int t, int* wsum) {
    int lane = t & 63, wid = t >> 6;
    int c0 = a[t * 4], c1 = a[t * 4 + 1], c2 = a[t * 4 + 2], c3 = a[t * 4 + 3];
    int tsum = c0 + c1 + c2 + c3, incl = tsum;
    #pragma unroll
    for (int off = 1; off < 64; off <<= 1) {
        int y = __shfl_up(incl, off);
        if (lane >= off) incl += y;
    }
    if (lane == 63) wsum[wid] = incl;
    __syncthreads();
    int wb = 0;
    #pragma unroll
    for (int w = 0; w < 4; w++) if (w < wid) wb += wsum[w];
    int excl = wb + incl - tsum;
    a[t * 4] = excl; a[t * 4 + 1] = excl + c0;
    a[t * 4 + 2] = excl + c0 + c1; a[t * 4 + 3] = excl + c0 + c1 + c2;
    __syncthreads();
}

// 1: per-(chunk,bucket) edge counts; no global atomics, XCD-contiguous chunks
__global__ __launch_bounds__(256) void count_chunk(const int* __restrict__ rows,
        int4 mlo, int4 mhi, int* __restrict__ lenTab, int NSB, int nchunks, int E) {
    __shared__ int hist[HISTP];
    int c = xcd_swz(blockIdx.x, nchunks), s = blockIdx.y, t = threadIdx.x;
    size_t sb = (size_t)smap8(mlo, mhi, s) * E;
    int e0 = c * CH, e1 = e0 + CH; if (e1 > E) e1 = E;
    for (int i = t; i < HISTP; i += 256) hist[i] = 0;
    __syncthreads();
    for (int e = e0 + t; e < e1; e += 256)
        atomicAdd(&hist[(uint)rows[sb + e] >> SBSHIFT], 1);
    __syncthreads();
    for (int b = t; b < NSB; b += 256)
        lenTab[((size_t)s * NSB + b) * nchunks + c] = hist[b];
}

// 1b: bucket totals by contiguous row-sum of lenTab (replaces global atomics)
__global__ __launch_bounds__(256) void btot_kernel(const int* __restrict__ lenTab,
        int* __restrict__ btot, int NSB, int nchunks) {
    int s = blockIdx.y;
    int b = blockIdx.x * 256 + threadIdx.x;
    if (b >= NSB) return;
    const int* lt = lenTab + ((size_t)s * NSB + b) * nchunks;
    int a0 = 0, a1 = 0, a2 = 0, a3 = 0;
    int c = 0;
    for (; c + 4 <= nchunks; c += 4) { a0 += lt[c]; a1 += lt[c+1]; a2 += lt[c+2]; a3 += lt[c+3]; }
    for (; c < nchunks; ++c) a0 += lt[c];
    btot[s * NSB + b] = a0 + a1 + a2 + a3;
}

// 2: bucket bases (exclusive scan of totals, + sentinel)
__global__ __launch_bounds__(256) void bucket_scanex(const int* __restrict__ btot,
        int* __restrict__ bbase, int NSB) {
    __shared__ int a[1024];
    __shared__ int wsum[4];
    int s = blockIdx.x, t = threadIdx.x;
    #pragma unroll
    for (int k = 0; k < 4; k++) {
        int i = t + k * 256;
        a[i] = (i < NSB) ? btot[s * NSB + i] : 0;
    }
    __syncthreads();
    block_scan1024(a, t, wsum);
    #pragma unroll
    for (int k = 0; k < 4; k++) {
        int i = t + k * 256;
        if (i <= NSB) bbase[s * (NSB + 1) + i] = a[i];
    }
}

// 3: per-(bucket,chunk) segment positions (prefix over chunks); wave per bucket
__global__ __launch_bounds__(64) void pos_scan(const int* __restrict__ lenTab,
        const int* __restrict__ bbase, int* __restrict__ segPos, int NSB, int nchunks) {
    int b = blockIdx.x, s = blockIdx.y, lane = threadIdx.x;
    const int* lt = lenTab + ((size_t)s * NSB + b) * nchunks;
    int* sp = segPos + ((size_t)s * NSB + b) * nchunks;
    int run = bbase[s * (NSB + 1) + b];
    for (int c0 = 0; c0 < nchunks; c0 += 64) {
        int c = c0 + lane;
        int v = (c < nchunks) ? lt[c] : 0;
        int incl = v;
        #pragma unroll
        for (int off = 1; off < 64; off <<= 1) {
            int y = __shfl_up(incl, off);
            if (lane >= off) incl += y;
        }
        if (c < nchunks) sp[c] = run + incl - v;
        run += __shfl(incl, 63);
    }
}

// 4: bin chunk in LDS, write bucket-major stage2 at precomputed slots
__global__ __launch_bounds__(256) void place_chunk(const int* __restrict__ rows,
        const int* __restrict__ cols, const float* __restrict__ vals,
        int4 mlo, int4 mhi, const int* __restrict__ segPos, int2* __restrict__ stage2,
        int NSB, int nchunks, int E) {
    __shared__ int2 sbuf[CH];
    __shared__ ushort bmap[CH];
    __shared__ int cur[1024];
    __shared__ int off[1024];
    __shared__ int spos[HISTP];
    __shared__ int wsum[4];
    int c = xcd_swz(blockIdx.x, nchunks), s = blockIdx.y, t = threadIdx.x;
    size_t sb = (size_t)smap8(mlo, mhi, s) * E;
    int e0 = c * CH, e1 = e0 + CH; if (e1 > E) e1 = E;
    int csz = e1 - e0;
    #pragma unroll
    for (int k = 0; k < 4; k++) cur[t + k * 256] = 0;
    __syncthreads();
    for (int e = e0 + t; e < e1; e += 256)
        atomicAdd(&cur[(uint)rows[sb + e] >> SBSHIFT], 1);
    __syncthreads();
    block_scan1024(cur, t, wsum);
    #pragma unroll
    for (int k = 0; k < 4; k++) { int i = t + k * 256; off[i] = cur[i]; }
    for (int b = t; b < NSB; b += 256)
        spos[b] = segPos[((size_t)s * NSB + b) * nchunks + c];
    __syncthreads();
    for (int e = e0 + t; e < e1; e += 256) {
        int r = rows[sb + e];
        int b = (uint)r >> SBSHIFT;
        int pos = atomicAdd(&cur[b], 1);
        uint cw = (uint)cols[sb + e] | ((uint)(r & (SBROWS - 1)) << 20);
        sbuf[pos] = make_int2((int)cw, __float_as_int(vals[sb + e]));
        bmap[pos] = (ushort)b;
    }
    __syncthreads();
    int2* dst = stage2 + (size_t)s * E;
    for (int i = t; i < csz; i += 256) {
        int b = bmap[i];
        dst[spos[b] + (i - off[b])] = sbuf[i];
    }
}

// 5: bucket contiguous in stage2 -> register-cached read, LDS place, row col-sort,
// single linear pk write.
__global__ __launch_bounds__(256) void fill_bucket(const int2* __restrict__ stage2,
        const int* __restrict__ bbase, int* __restrict__ rp, int2* __restrict__ pk,
        int NSB, int N, int E) {
    __shared__ int2 sbuf[SBUF_CAP];
    __shared__ int cur[128];
    __shared__ int loc[132];
    __shared__ int wsum2[2];
    int b = blockIdx.x, s = blockIdx.y, t = threadIdx.x;
    int lane = t & 63, wid = t >> 6;
    int rowbase = b << SBSHIFT;
    int nrows = N - rowbase; if (nrows > SBROWS) nrows = SBROWS;
    size_t sb = (size_t)s * E;
    int beg = bbase[s * (NSB + 1) + b];
    int end = bbase[s * (NSB + 1) + b + 1];
    int tot = end - beg;
    if (t < 128) cur[t] = 0;
    __syncthreads();
    int2 myE[CACHE_PT];
    #pragma unroll
    for (int k = 0; k < CACHE_PT; k++) {
        int idx = t + k * 256;
        if (idx < tot) {
            int2 u = stage2[sb + beg + idx];
            myE[k] = u;
            atomicAdd(&cur[((uint)u.x) >> 20], 1);
        }
    }
    for (int idx = t + CACHE_PT * 256; idx < tot; idx += 256) {
        int2 u = stage2[sb + beg + idx];
        atomicAdd(&cur[((uint)u.x) >> 20], 1);
    }
    __syncthreads();
    int v = 0, incl = 0;
    if (t < 128) {
        v = cur[t]; incl = v;
        #pragma unroll
        for (int off = 1; off < 64; off <<= 1) {
            int y = __shfl_up(incl, off);
            if (lane >= off) incl += y;
        }
        if (lane == 63) wsum2[wid] = incl;
    }
    __syncthreads();
    if (t < 128) {
        int excl = incl - v + ((wid == 1) ? wsum2[0] : 0);
        loc[t] = excl; cur[t] = excl;
        if (t < nrows) rp[(size_t)s * (N + 1) + rowbase + t] = beg + excl;
    }
    if (t == 0) loc[128] = tot;
    if (b == 0 && t == 0) rp[(size_t)s * (N + 1) + N] = E;
    __syncthreads();
    #pragma unroll
    for (int k = 0; k < CACHE_PT; k++) {
        int idx = t + k * 256;
        if (idx < tot) {
            int2 u = myE[k];
            int lr = ((uint)u.x) >> 20;
            int pos = atomicAdd(&cur[lr], 1);
            int2 w = make_int2(u.x & 0xFFFFF, u.y);
            if (pos < SBUF_CAP) sbuf[pos] = w; else pk[sb + beg + pos] = w;
        }
    }
    for (int idx = t + CACHE_PT * 256; idx < tot; idx += 256) {
        int2 u = stage2[sb + beg + idx];
        int lr = ((uint)u.x) >> 20;
        int pos = atomicAdd(&cur[lr], 1);
        int2 w = make_int2(u.x & 0xFFFFF, u.y);
        if (pos < SBUF_CAP) sbuf[pos] = w; else pk[sb + beg + pos] = w;
    }
    __syncthreads();
    for (int r = wid; r < nrows; r += 4) {
        int rb = loc[r], re = loc[r + 1];
        int deg = re - rb;
        if (deg < 2 || deg > 64 || re > SBUF_CAP) continue;
        int key = 0x7FFFFFFF, val = 0;
        if (lane < deg) { int2 u = sbuf[rb + lane]; key = u.x; val = u.y; }
        #pragma unroll
        for (int k = 2; k <= 64; k <<= 1) {
            #pragma unroll
            for (int j = k >> 1; j > 0; j >>= 1) {
                int okey = __shfl_xor(key, j);
                int oval = __shfl_xor(val, j);
                bool up = ((lane & k) == 0);
                bool lower = ((lane & j) == 0);
                bool keepmin = (lower == up);
                bool take = keepmin ? (okey < key) : (okey > key);
                if (take) { key = okey; val = oval; }
            }
        }
        if (lane < deg) sbuf[rb + lane] = make_int2(key, val);
    }
    __syncthreads();
    int lim = (tot < SBUF_CAP) ? tot : SBUF_CAP;
    for (int i = t; i < lim; i += 256)
        __builtin_nontemporal_store(*(const long long*)&sbuf[i], (long long*)&pk[sb + beg + i]);
}

// ---------------- fused SpMM kernels (persistent, sorted-walk, MLP=4) ----------------

__device__ __forceinline__ void row_gather_sum(const int2* __restrict__ pk,
        int e, int end, const uint* __restrict__ Xb, int lane,
        float& ax, float& ay) {
    for (; e + 4 <= end; e += 4) {
        int2 c0 = ldnt(&pk[e]);     int2 c1 = ldnt(&pk[e + 1]);
        int2 c2 = ldnt(&pk[e + 2]); int2 c3 = ldnt(&pk[e + 3]);
        uint u0 = Xb[(c0.x << 6) + lane]; uint u1 = Xb[(c1.x << 6) + lane];
        uint u2 = Xb[(c2.x << 6) + lane]; uint u3 = Xb[(c3.x << 6) + lane];
        float v0 = __int_as_float(c0.y), v1 = __int_as_float(c1.y);
        float v2 = __int_as_float(c2.y), v3 = __int_as_float(c3.y);
        ax = fmaf(v0, bfl(u0), ax); ay = fmaf(v0, bfh(u0), ay);
        ax = fmaf(v1, bfl(u1), ax); ay = fmaf(v1, bfh(u1), ay);
        ax = fmaf(v2, bfl(u2), ax); ay = fmaf(v2, bfh(u2), ay);
        ax = fmaf(v3, bfl(u3), ax); ay = fmaf(v3, bfh(u3), ay);
    }
    for (; e < end; ++e) {
        int2 c0 = ldnt(&pk[e]);
        uint u0 = Xb[(c0.x << 6) + lane];
        float v0 = __int_as_float(c0.y);
        ax = fmaf(v0, bfl(u0), ax); ay = fmaf(v0, bfh(u0), ay);
    }
}

__device__ __forceinline__ void row_gather_bp(const int2* __restrict__ pk,
        int e, int end, const uint* __restrict__ Xb, int lane,
        float& sx, float& sy, float& qx, float& qy) {
    for (; e + 4 <= end; e += 4) {
        int2 c0 = ldnt(&pk[e]);     int2 c1 = ldnt(&pk[e + 1]);
        int2 c2 = ldnt(&pk[e + 2]); int2 c3 = ldnt(&pk[e + 3]);
        uint u0 = Xb[(c0.x << 6) + lane]; uint u1 = Xb[(c1.x << 6) + lane];
        uint u2 = Xb[(c2.x << 6) + lane]; uint u3 = Xb[(c3.x << 6) + lane];
        float v0 = __int_as_float(c0.y), v1 = __int_as_float(c1.y);
        float v2 = __int_as_float(c2.y), v3 = __int_as_float(c3.y);
        float x0 = bfl(u0), y0 = bfh(u0), x1 = bfl(u1), y1 = bfh(u1);
        float x2 = bfl(u2), y2 = bfh(u2), x3 = bfl(u3), y3 = bfh(u3);
        sx = fmaf(v0, x0, sx); sy = fmaf(v0, y0, sy);
        qx = fmaf(v0 * x0, x0, qx); qy = fmaf(v0 * y0, y0, qy);
        sx = fmaf(v1, x1, sx); sy = fmaf(v1, y1, sy);
        qx = fmaf(v1 * x1, x1, qx); qy = fmaf(v1 * y1, y1, qy);
        sx = fmaf(v2, x2, sx); sy = fmaf(v2, y2, sy);
        qx = fmaf(v2 * x2, x2, qx); qy = fmaf(v2 * y2, y2, qy);
        sx = fmaf(v3, x3, sx); sy = fmaf(v3, y3, sy);
        qx = fmaf(v3 * x3, x3, qx); qy = fmaf(v3 * y3, y3, qy);
    }
    for (; e < end; ++e) {
        int2 c0 = ldnt(&pk[e]);
        uint u0 = Xb[(c0.x << 6) + lane];
        float v0 = __int_as_float(c0.y);
        float x0 = bfl(u0), y0 = bfh(u0);
        sx = fmaf(v0, x0, sx); sy = fmaf(v0, y0, sy);
        qx = fmaf(v0 * x0, x0, qx); qy = fmaf(v0 * y0, y0, qy);
    }
}

__global__ __launch_bounds__(256) void spmm_bp2(const int* __restrict__ rpA,
        const int2* __restrict__ pkA, const int* __restrict__ rpB,
        const int2* __restrict__ pkB, const uint* __restrict__ Xb,
        uint* __restrict__ outb, int N) {
    int w = threadIdx.x >> 6, lane = threadIdx.x & 63;
    int stride = gridDim.x * 4;
    for (int row = blockIdx.x * 4 + w; row < N; row += stride) {
        float sax = 0.f, say = 0.f, qax = 0.f, qay = 0.f;
        float sbx = 0.f, sby = 0.f, qbx = 0.f, qby = 0.f;
        row_gather_bp(pkA, rpA[row], rpA[row + 1], Xb, lane, sax, say, qax, qay);
        row_gather_bp(pkB, rpB[row], rpB[row + 1], Xb, lane, sbx, sby, qbx, qby);
        float tx = 0.5f * ((sax * sax - qax) - (sbx * sbx - qbx));
        float ty = 0.5f * ((say * say - qay) - (sby * sby - qby));
        outb[((size_t)row << 6) + lane] = packbf2(tx, ty);
    }
}

__global__ __launch_bounds__(256) void spmm_out(const int* __restrict__ rp0,
        const int2* __restrict__ pk0, const int* __restrict__ rp5,
        const int2* __restrict__ pk5, const int* __restrict__ rp6,
        const int2* __restrict__ pk6, const uint* __restrict__ Pb,
        const uint* __restrict__ t1b, const uint* __restrict__ t2b,
        float* __restrict__ out, int N) {
    int w = threadIdx.x >> 6, lane = threadIdx.x & 63;
    int stride = gridDim.x * 4;
    for (int row = blockIdx.x * 4 + w; row < N; row += stride) {
        float a0x = 0.f, a0y = 0.f, a5x = 0.f, a5y = 0.f, a6x = 0.f, a6y = 0.f;
        row_gather_sum(pk0, rp0[row], rp0[row + 1], Pb,  lane, a0x, a0y);
        row_gather_sum(pk5, rp5[row], rp5[row + 1], t1b, lane, a5x, a5y);
        row_gather_sum(pk6, rp6[row], rp6[row + 1], t2b, lane, a6x, a6y);
        float rx = fmaxf(0.5f * a0x + 0.25f * a5x + 0.25f * a6x, 0.f);
        float ry = fmaxf(0.5f * a0y + 0.25f * a5y + 0.25f * a6y, 0.f);
        *(float2*)(out + ((size_t)row << 7) + (lane << 1)) = make_float2(rx, ry);
    }
}

// ---------------- launch ----------------

extern "C" void kernel_launch(void* const* d_in, const int* in_sizes, int n_in,
                              void* d_out, int out_size, void* d_ws, size_t ws_size,
                              hipStream_t stream) {
    (void)n_in; (void)out_size;
    const float* x   = (const float*)d_in[0];
    const float* Wa  = (const float*)d_in[1];
    const float* Wb  = (const float*)d_in[2];
    const float* w1  = (const float*)d_in[4];
    const float* b1  = (const float*)d_in[5];
    const float* w2  = (const float*)d_in[6];
    const int* rows  = (const int*)d_in[7];
    const int* cols  = (const int*)d_in[8];
    const float* vals = (const float*)d_in[9];
    float* out = (float*)d_out;

    const int N = in_sizes[0] / 256;
    const int E = in_sizes[7] / 7;
    const int NSB = (N + SBROWS - 1) >> SBSHIFT;
    const int nchunks = (E + CH - 1) / CH;

    auto layoutBytes = [&](int ns) -> size_t {
        size_t bts = 3 * (size_t)N * 64 * 4;                   // Pb,t1b,t2b
        bts += (size_t)ns * E * 8;                             // pk
        size_t region = (size_t)N * 1024;                      // AB
        if ((size_t)ns * E * 8 > region) region = (size_t)ns * E * 8;  // stage2
        bts += region;
        bts += (size_t)ns * (N + 1) * 4;                       // rp
        bts += 2 * (size_t)ns * NSB * (size_t)nchunks * 4;     // lenTab + segPos
        bts += (size_t)ns * NSB * 4;                           // btot
        bts += (size_t)ns * (NSB + 1) * 4;                     // bbase
        return bts + 4096;
    };
    const int NSUP = (ws_size >= layoutBytes(7)) ? 7 : 4;

    uint* Pb  = (uint*)d_ws;
    uint* t1b = Pb + (size_t)N * 64;
    uint* t2b = t1b + (size_t)N * 64;
    int2* pk  = (int2*)(t2b + (size_t)N * 64);
    size_t regionFloats = (size_t)N * 256;
    if ((size_t)NSUP * E * 2 > regionFloats) regionFloats = (size_t)NSUP * E * 2;
    int2* stage2 = pk + (size_t)NSUP * E;
    float* AB    = (float*)stage2;
    int* rp      = (int*)((float*)stage2 + regionFloats);
    int* lenTab  = rp + (size_t)NSUP * (N + 1);
    int* segPos  = lenTab + (size_t)NSUP * NSB * nchunks;
    int* btot    = segPos + (size_t)NSUP * NSB * nchunks;
    int* bbase   = btot + (size_t)NSUP * NSB;

    dim3 b256(256);
    int sgrid = (N + 3) / 4;
    int pgrid = PGRID; if (pgrid > sgrid) pgrid = sgrid;
    int bgrid = (NSB + 255) / 256;

    gemm_kernel<<<(N + BM - 1) / BM, b256, 0, stream>>>(x, Wa, Wb, AB, N);
    attn_kernel<<<sgrid, b256, 0, stream>>>(AB, w1, b1, w2, Pb, N);

    auto build = [&](int4 mlo, int4 mhi, int nsup) {
        count_chunk<<<dim3(nchunks, nsup), b256, 0, stream>>>(rows, mlo, mhi, lenTab,
                                                              NSB, nchunks, E);
        btot_kernel<<<dim3(bgrid, nsup), b256, 0, stream>>>(lenTab, btot, NSB, nchunks);
        bucket_scanex<<<nsup, b256, 0, stream>>>(btot, bbase, NSB);
        pos_scan<<<dim3(NSB, nsup), dim3(64), 0, stream>>>(lenTab, bbase, segPos, NSB, nchunks);
        place_chunk<<<dim3(nchunks, nsup), b256, 0, stream>>>(rows, cols, vals, mlo, mhi,
                                                              segPos, stage2, NSB, nchunks, E);
        fill_bucket<<<dim3(NSB, nsup), b256, 0, stream>>>(stage2, bbase, rp, pk, NSB, N, E);
    };

    const size_t NP1 = (size_t)(N + 1);

    if (NSUP == 7) {
        // one build for all 7 supports: slots {1,3,2,4,0,5,6}
        build(make_int4(1, 3, 2, 4), make_int4(0, 5, 6, 6), 7);
        spmm_bp2<<<pgrid, b256, 0, stream>>>(rp + 0 * NP1, pk + 0 * (size_t)E,
                                             rp + 1 * NP1, pk + 1 * (size_t)E, Pb, t1b, N);
        spmm_bp2<<<pgrid, b256, 0, stream>>>(rp + 2 * NP1, pk + 2 * (size_t)E,
                                             rp + 3 * NP1, pk + 3 * (size_t)E, Pb, t2b, N);
        spmm_out<<<pgrid, b256, 0, stream>>>(rp + 4 * NP1, pk + 4 * (size_t)E,
                                             rp + 5 * NP1, pk + 5 * (size_t)E,
                                             rp + 6 * NP1, pk + 6 * (size_t)E,
                                             Pb, t1b, t2b, out, N);
    } else {
        // fallback: two build groups (proven r11 path)
        build(make_int4(1, 3, 2, 4), make_int4(0, 0, 0, 0), 4);
        spmm_bp2<<<pgrid, b256, 0, stream>>>(rp + 0 * NP1, pk + 0 * (size_t)E,
                                             rp + 1 * NP1, pk + 1 * (size_t)E, Pb, t1b, N);
        spmm_bp2<<<pgrid, b256, 0, stream>>>(rp + 2 * NP1, pk + 2 * (size_t)E,
                                             rp + 3 * NP1, pk + 3 * (size_t)E, Pb, t2b, N);
        build(make_int4(0, 5, 6, 6), make_int4(0, 0, 0, 0), 3);
        spmm_out<<<pgrid, b256, 0, stream>>>(rp + 0 * NP1, pk + 0 * (size_t)E,
                                             rp + 1 * NP1, pk + 1 * (size_t)E,
                                             rp + 2 * NP1, pk + 2 * (size_t)E,
                                             Pb, t1b, t2b, out, N);
    }
}

// Round 13
// 2157.507 us; speedup vs baseline: 1.1380x; 1.0014x over previous
//
#include <hip/hip_runtime.h>

typedef unsigned int uint;
typedef unsigned short ushort;

__device__ __forceinline__ float bfl(uint u){ return __uint_as_float(u << 16); }
__device__ __forceinline__ float bfh(uint u){ return __uint_as_float(u & 0xFFFF0000u); }
__device__ __forceinline__ uint f2bfbits(float f){
    uint b = __float_as_uint(f);
    return (b + 0x7FFFu + ((b >> 16) & 1u)) >> 16;
}
__device__ __forceinline__ uint packbf2(float a, float b){
    return f2bfbits(a) | (f2bfbits(b) << 16);
}
__device__ __forceinline__ int smap8(int4 lo, int4 hi, int s){
    int4 m = (s < 4) ? lo : hi;
    int k = s & 3;
    return (k == 0) ? m.x : (k == 1) ? m.y : (k == 2) ? m.z : m.w;
}
__device__ __forceinline__ int2 ldnt(const int2* p){
    long long v = __builtin_nontemporal_load((const long long*)p);
    int2 r; r.x = (int)(v & 0xFFFFFFFFll); r.y = (int)(v >> 32); return r;
}
// bijective XCD-contiguous chunk swizzle
__device__ __forceinline__ int xcd_swz(int bid, int n){
    int q = n >> 3, r = n & 7;
    int x = bid & 7, i = bid >> 3;
    return (x < r) ? (x * (q + 1) + i) : (r * (q + 1) + (x - r) * q + i);
}

#define CH 6144
#define SBSHIFT 7
#define SBROWS 128
#define HISTP 784
#define SBUF_CAP 5120
#define CACHE_PT 20
#define PGRID 2048

// ---------------- dense part ----------------

#define BM 64
#define BK 32
__global__ __launch_bounds__(256) void gemm_kernel(const float* __restrict__ x,
                                                   const float* __restrict__ Wa,
                                                   const float* __restrict__ Wb,
                                                   float* __restrict__ AB, int N) {
    __shared__ float xsT[BK][BM + 4];
    __shared__ float wsm[BK][256];
    int t = threadIdx.x;
    int rowbase = blockIdx.x * BM;
    int tx = t & 15, ty = t >> 4;
    float acc[4][16];
    #pragma unroll
    for (int i = 0; i < 4; i++)
        #pragma unroll
        for (int j = 0; j < 16; j++) acc[i][j] = 0.f;

    for (int k0 = 0; k0 < 256; k0 += BK) {
        {
            int r = t & 63;
            int koff = (t >> 6) * 8;
            int gr = rowbase + r; if (gr >= N) gr = N - 1;
            const float* src = x + (size_t)gr * 256 + k0 + koff;
            float4 u0 = *(const float4*)(src);
            float4 u1 = *(const float4*)(src + 4);
            xsT[koff + 0][r] = u0.x; xsT[koff + 1][r] = u0.y;
            xsT[koff + 2][r] = u0.z; xsT[koff + 3][r] = u0.w;
            xsT[koff + 4][r] = u1.x; xsT[koff + 5][r] = u1.y;
            xsT[koff + 6][r] = u1.z; xsT[koff + 7][r] = u1.w;
        }
        {
            #pragma unroll
            for (int i = 0; i < 8; i++) {
                int f = t + i * 256;
                int rr = f >> 6, c4 = f & 63;
                const float* src = (c4 < 32) ? &Wa[(size_t)(k0 + rr) * 128 + c4 * 4]
                                             : &Wb[(size_t)(k0 + rr) * 128 + (c4 - 32) * 4];
                *(float4*)&wsm[rr][c4 * 4] = *(const float4*)src;
            }
        }
        __syncthreads();
        #pragma unroll
        for (int kk = 0; kk < BK; ++kk) {
            float4 a = *(const float4*)&xsT[kk][ty * 4];
            float av[4] = {a.x, a.y, a.z, a.w};
            float bv[16];
            #pragma unroll
            for (int q = 0; q < 4; q++)
                *(float4*)&bv[q * 4] = *(const float4*)&wsm[kk][q * 64 + tx * 4];
            #pragma unroll
            for (int i = 0; i < 4; i++)
                #pragma unroll
                for (int j = 0; j < 16; j++)
                    acc[i][j] = fmaf(av[i], bv[j], acc[i][j]);
        }
        __syncthreads();
    }
    #pragma unroll
    for (int i = 0; i < 4; i++) {
        int gr = rowbase + ty * 4 + i;
        if (gr < N) {
            #pragma unroll
            for (int q = 0; q < 4; q++) {
                float4 o = {acc[i][q*4], acc[i][q*4+1], acc[i][q*4+2], acc[i][q*4+3]};
                *(float4*)&AB[(size_t)gr * 256 + q * 64 + tx * 4] = o;
            }
        }
    }
}

// attention: Pb[n] packed bf16 [N][128]
__global__ __launch_bounds__(256) void attn_kernel(const float* __restrict__ AB,
        const float* __restrict__ w1, const float* __restrict__ b1,
        const float* __restrict__ w2, uint* __restrict__ Pb, int N) {
    __shared__ float w1s[128 * 32];
    __shared__ float b1s[32], w2s[32];
    __shared__ float aS[4][128], alS[4][128];
    int t = threadIdx.x;
    #pragma unroll
    for (int i = 0; i < 16; i++) w1s[t + i * 256] = w1[t + i * 256];
    if (t < 32) { b1s[t] = b1[t]; w2s[t] = w2[t]; }

    int w = t >> 6, lane = t & 63;
    int node = blockIdx.x * 4 + w;
    bool active = node < N;
    int nclamp = active ? node : (N - 1);
    float2 a = *(const float2*)(AB + (size_t)nclamp * 256 + lane * 2);
    float2 b = *(const float2*)(AB + (size_t)nclamp * 256 + 128 + lane * 2);
    float2 al;
    al.x = a.x + 0.5f * (a.x * a.x - a.x * b.x);
    al.y = a.y + 0.5f * (a.y * a.y - a.y * b.y);
    aS[w][lane * 2] = a.x;   aS[w][lane * 2 + 1] = a.y;
    alS[w][lane * 2] = al.x; alS[w][lane * 2 + 1] = al.y;
    __syncthreads();

    int j = lane & 31;
    const float* src = (lane < 32) ? aS[w] : alS[w];
    float acc = b1s[j];
    #pragma unroll 8
    for (int d = 0; d < 128; ++d) acc = fmaf(src[d], w1s[d * 32 + j], acc);
    float h = tanhf(acc);
    float prod = h * w2s[j];
    #pragma unroll
    for (int off = 1; off < 32; off <<= 1) prod += __shfl_xor(prod, off);
    float eo = __shfl_xor(prod, 32);
    float e0 = (lane < 32) ? prod : eo;
    float e1 = (lane < 32) ? eo : prod;
    float m = fmaxf(e0, e1);
    float p0 = expf(e0 - m), p1 = expf(e1 - m);
    float inv = 1.0f / (p0 + p1);
    float at0 = p0 * inv, at1 = p1 * inv;
    if (active) {
        float px = at0 * a.x + at1 * al.x;
        float py = at0 * a.y + at1 * al.y;
        Pb[(size_t)node * 64 + lane] = packbf2(px, py);
    }
}

// ---------------- CSR build (bucket-major reorder, zero global atomics) ----------------

__device__ __forceinline__ void block_scan1024(int* a, int t, int* wsum) {
    int lane = t & 63, wid = t >> 6;
    int c0 = a[t * 4], c1 = a[t * 4 + 1], c2 = a[t * 4 + 2], c3 = a[t * 4 + 3];
    int tsum = c0 + c1 + c2 + c3, incl = tsum;
    #pragma unroll
    for (int off = 1; off < 64; off <<= 1) {
        int y = __shfl_up(incl, off);
        if (lane >= off) incl += y;
    }
    if (lane == 63) wsum[wid] = incl;
    __syncthreads();
    int wb = 0;
    #pragma unroll
    for (int w = 0; w < 4; w++) if (w < wid) wb += wsum[w];
    int excl = wb + incl - tsum;
    a[t * 4] = excl; a[t * 4 + 1] = excl + c0;
    a[t * 4 + 2] = excl + c0 + c1; a[t * 4 + 3] = excl + c0 + c1 + c2;
    __syncthreads();
}

__global__ __launch_bounds__(256) void count_chunk(const int* __restrict__ rows,
        int4 mlo, int4 mhi, int* __restrict__ lenTab, int NSB, int nchunks, int E) {
    __shared__ int hist[HISTP];
    int c = xcd_swz(blockIdx.x, nchunks), s = blockIdx.y, t = threadIdx.x;
    size_t sb = (size_t)smap8(mlo, mhi, s) * E;
    int e0 = c * CH, e1 = e0 + CH; if (e1 > E) e1 = E;
    for (int i = t; i < HISTP; i += 256) hist[i] = 0;
    __syncthreads();
    for (int e = e0 + t; e < e1; e += 256)
        atomicAdd(&hist[(uint)rows[sb + e] >> SBSHIFT], 1);
    __syncthreads();
    for (int b = t; b < NSB; b += 256)
        lenTab[((size_t)s * NSB + b) * nchunks + c] = hist[b];
}

__global__ __launch_bounds__(256) void btot_kernel(const int* __restrict__ lenTab,
        int* __restrict__ btot, int NSB, int nchunks) {
    int s = blockIdx.y;
    int b = blockIdx.x * 256 + threadIdx.x;
    if (b >= NSB) return;
    const int* lt = lenTab + ((size_t)s * NSB + b) * nchunks;
    int a0 = 0, a1 = 0, a2 = 0, a3 = 0;
    int c = 0;
    for (; c + 4 <= nchunks; c += 4) { a0 += lt[c]; a1 += lt[c+1]; a2 += lt[c+2]; a3 += lt[c+3]; }
    for (; c < nchunks; ++c) a0 += lt[c];
    btot[s * NSB + b] = a0 + a1 + a2 + a3;
}

__global__ __launch_bounds__(256) void bucket_scanex(const int* __restrict__ btot,
        int* __restrict__ bbase, int NSB) {
    __shared__ int a[1024];
    __shared__ int wsum[4];
    int s = blockIdx.x, t = threadIdx.x;
    #pragma unroll
    for (int k = 0; k < 4; k++) {
        int i = t + k * 256;
        a[i] = (i < NSB) ? btot[s * NSB + i] : 0;
    }
    __syncthreads();
    block_scan1024(a, t, wsum);
    #pragma unroll
    for (int k = 0; k < 4; k++) {
        int i = t + k * 256;
        if (i <= NSB) bbase[s * (NSB + 1) + i] = a[i];
    }
}

__global__ __launch_bounds__(64) void pos_scan(const int* __restrict__ lenTab,
        const int* __restrict__ bbase, int* __restrict__ segPos, int NSB, int nchunks) {
    int b = blockIdx.x, s = blockIdx.y, lane = threadIdx.x;
    const int* lt = lenTab + ((size_t)s * NSB + b) * nchunks;
    int* sp = segPos + ((size_t)s * NSB + b) * nchunks;
    int run = bbase[s * (NSB + 1) + b];
    for (int c0 = 0; c0 < nchunks; c0 += 64) {
        int c = c0 + lane;
        int v = (c < nchunks) ? lt[c] : 0;
        int incl = v;
        #pragma unroll
        for (int off = 1; off < 64; off <<= 1) {
            int y = __shfl_up(incl, off);
            if (lane >= off) incl += y;
        }
        if (c < nchunks) sp[c] = run + incl - v;
        run += __shfl(incl, 63);
    }
}

__global__ __launch_bounds__(256) void place_chunk(const int* __restrict__ rows,
        const int* __restrict__ cols, const float* __restrict__ vals,
        int4 mlo, int4 mhi, const int* __restrict__ segPos, int2* __restrict__ stage2,
        int NSB, int nchunks, int E) {
    __shared__ int2 sbuf[CH];
    __shared__ ushort bmap[CH];
    __shared__ int cur[1024];
    __shared__ int off[1024];
    __shared__ int spos[HISTP];
    __shared__ int wsum[4];
    int c = xcd_swz(blockIdx.x, nchunks), s = blockIdx.y, t = threadIdx.x;
    size_t sb = (size_t)smap8(mlo, mhi, s) * E;
    int e0 = c * CH, e1 = e0 + CH; if (e1 > E) e1 = E;
    int csz = e1 - e0;
    #pragma unroll
    for (int k = 0; k < 4; k++) cur[t + k * 256] = 0;
    __syncthreads();
    for (int e = e0 + t; e < e1; e += 256)
        atomicAdd(&cur[(uint)rows[sb + e] >> SBSHIFT], 1);
    __syncthreads();
    block_scan1024(cur, t, wsum);
    #pragma unroll
    for (int k = 0; k < 4; k++) { int i = t + k * 256; off[i] = cur[i]; }
    for (int b = t; b < NSB; b += 256)
        spos[b] = segPos[((size_t)s * NSB + b) * nchunks + c];
    __syncthreads();
    for (int e = e0 + t; e < e1; e += 256) {
        int r = rows[sb + e];
        int b = (uint)r >> SBSHIFT;
        int pos = atomicAdd(&cur[b], 1);
        uint cw = (uint)cols[sb + e] | ((uint)(r & (SBROWS - 1)) << 20);
        sbuf[pos] = make_int2((int)cw, __float_as_int(vals[sb + e]));
        bmap[pos] = (ushort)b;
    }
    __syncthreads();
    int2* dst = stage2 + (size_t)s * E;
    for (int i = t; i < csz; i += 256) {
        int b = bmap[i];
        dst[spos[b] + (i - off[b])] = sbuf[i];
    }
}

__global__ __launch_bounds__(256) void fill_bucket(const int2* __restrict__ stage2,
        const int* __restrict__ bbase, int* __restrict__ rp, int2* __restrict__ pk,
        int NSB, int N, int E) {
    __shared__ int2 sbuf[SBUF_CAP];
    __shared__ int cur[128];
    __shared__ int loc[132];
    __shared__ int wsum2[2];
    int b = blockIdx.x, s = blockIdx.y, t = threadIdx.x;
    int lane = t & 63, wid = t >> 6;
    int rowbase = b << SBSHIFT;
    int nrows = N - rowbase; if (nrows > SBROWS) nrows = SBROWS;
    size_t sb = (size_t)s * E;
    int beg = bbase[s * (NSB + 1) + b];
    int end = bbase[s * (NSB + 1) + b + 1];
    int tot = end - beg;
    if (t < 128) cur[t] = 0;
    __syncthreads();
    int2 myE[CACHE_PT];
    #pragma unroll
    for (int k = 0; k < CACHE_PT; k++) {
        int idx = t + k * 256;
        if (idx < tot) {
            int2 u = stage2[sb + beg + idx];
            myE[k] = u;
            atomicAdd(&cur[((uint)u.x) >> 20], 1);
        }
    }
    for (int idx = t + CACHE_PT * 256; idx < tot; idx += 256) {
        int2 u = stage2[sb + beg + idx];
        atomicAdd(&cur[((uint)u.x) >> 20], 1);
    }
    __syncthreads();
    int v = 0, incl = 0;
    if (t < 128) {
        v = cur[t]; incl = v;
        #pragma unroll
        for (int off = 1; off < 64; off <<= 1) {
            int y = __shfl_up(incl, off);
            if (lane >= off) incl += y;
        }
        if (lane == 63) wsum2[wid] = incl;
    }
    __syncthreads();
    if (t < 128) {
        int excl = incl - v + ((wid == 1) ? wsum2[0] : 0);
        loc[t] = excl; cur[t] = excl;
        if (t < nrows) rp[(size_t)s * (N + 1) + rowbase + t] = beg + excl;
    }
    if (t == 0) loc[128] = tot;
    if (b == 0 && t == 0) rp[(size_t)s * (N + 1) + N] = E;
    __syncthreads();
    #pragma unroll
    for (int k = 0; k < CACHE_PT; k++) {
        int idx = t + k * 256;
        if (idx < tot) {
            int2 u = myE[k];
            int lr = ((uint)u.x) >> 20;
            int pos = atomicAdd(&cur[lr], 1);
            int2 w = make_int2(u.x & 0xFFFFF, u.y);
            if (pos < SBUF_CAP) sbuf[pos] = w; else pk[sb + beg + pos] = w;
        }
    }
    for (int idx = t + CACHE_PT * 256; idx < tot; idx += 256) {
        int2 u = stage2[sb + beg + idx];
        int lr = ((uint)u.x) >> 20;
        int pos = atomicAdd(&cur[lr], 1);
        int2 w = make_int2(u.x & 0xFFFFF, u.y);
        if (pos < SBUF_CAP) sbuf[pos] = w; else pk[sb + beg + pos] = w;
    }
    __syncthreads();
    for (int r = wid; r < nrows; r += 4) {
        int rb = loc[r], re = loc[r + 1];
        int deg = re - rb;
        if (deg < 2 || deg > 64 || re > SBUF_CAP) continue;
        int key = 0x7FFFFFFF, val = 0;
        if (lane < deg) { int2 u = sbuf[rb + lane]; key = u.x; val = u.y; }
        #pragma unroll
        for (int k = 2; k <= 64; k <<= 1) {
            #pragma unroll
            for (int j = k >> 1; j > 0; j >>= 1) {
                int okey = __shfl_xor(key, j);
                int oval = __shfl_xor(val, j);
                bool up = ((lane & k) == 0);
                bool lower = ((lane & j) == 0);
                bool keepmin = (lower == up);
                bool take = keepmin ? (okey < key) : (okey > key);
                if (take) { key = okey; val = oval; }
            }
        }
        if (lane < deg) sbuf[rb + lane] = make_int2(key, val);
    }
    __syncthreads();
    int lim = (tot < SBUF_CAP) ? tot : SBUF_CAP;
    for (int i = t; i < lim; i += 256)
        __builtin_nontemporal_store(*(const long long*)&sbuf[i], (long long*)&pk[sb + beg + i]);
}

// ---------------- fused SpMM kernels (persistent, sorted-walk, MLP=4) ----------------

__device__ __forceinline__ void row_gather_sum(const int2* __restrict__ pk,
        int e, int end, const uint* __restrict__ Xb, int lane,
        float& ax, float& ay) {
    for (; e + 4 <= end; e += 4) {
        int2 c0 = ldnt(&pk[e]);     int2 c1 = ldnt(&pk[e + 1]);
        int2 c2 = ldnt(&pk[e + 2]); int2 c3 = ldnt(&pk[e + 3]);
        uint u0 = Xb[(c0.x << 6) + lane]; uint u1 = Xb[(c1.x << 6) + lane];
        uint u2 = Xb[(c2.x << 6) + lane]; uint u3 = Xb[(c3.x << 6) + lane];
        float v0 = __int_as_float(c0.y), v1 = __int_as_float(c1.y);
        float v2 = __int_as_float(c2.y), v3 = __int_as_float(c3.y);
        ax = fmaf(v0, bfl(u0), ax); ay = fmaf(v0, bfh(u0), ay);
        ax = fmaf(v1, bfl(u1), ax); ay = fmaf(v1, bfh(u1), ay);
        ax = fmaf(v2, bfl(u2), ax); ay = fmaf(v2, bfh(u2), ay);
        ax = fmaf(v3, bfl(u3), ax); ay = fmaf(v3, bfh(u3), ay);
    }
    for (; e < end; ++e) {
        int2 c0 = ldnt(&pk[e]);
        uint u0 = Xb[(c0.x << 6) + lane];
        float v0 = __int_as_float(c0.y);
        ax = fmaf(v0, bfl(u0), ax); ay = fmaf(v0, bfh(u0), ay);
    }
}

__device__ __forceinline__ void row_gather_bp(const int2* __restrict__ pk,
        int e, int end, const uint* __restrict__ Xb, int lane,
        float& sx, float& sy, float& qx, float& qy) {
    for (; e + 4 <= end; e += 4) {
        int2 c0 = ldnt(&pk[e]);     int2 c1 = ldnt(&pk[e + 1]);
        int2 c2 = ldnt(&pk[e + 2]); int2 c3 = ldnt(&pk[e + 3]);
        uint u0 = Xb[(c0.x << 6) + lane]; uint u1 = Xb[(c1.x << 6) + lane];
        uint u2 = Xb[(c2.x << 6) + lane]; uint u3 = Xb[(c3.x << 6) + lane];
        float v0 = __int_as_float(c0.y), v1 = __int_as_float(c1.y);
        float v2 = __int_as_float(c2.y), v3 = __int_as_float(c3.y);
        float x0 = bfl(u0), y0 = bfh(u0), x1 = bfl(u1), y1 = bfh(u1);
        float x2 = bfl(u2), y2 = bfh(u2), x3 = bfl(u3), y3 = bfh(u3);
        sx = fmaf(v0, x0, sx); sy = fmaf(v0, y0, sy);
        qx = fmaf(v0 * x0, x0, qx); qy = fmaf(v0 * y0, y0, qy);
        sx = fmaf(v1, x1, sx); sy = fmaf(v1, y1, sy);
        qx = fmaf(v1 * x1, x1, qx); qy = fmaf(v1 * y1, y1, qy);
        sx = fmaf(v2, x2, sx); sy = fmaf(v2, y2, sy);
        qx = fmaf(v2 * x2, x2, qx); qy = fmaf(v2 * y2, y2, qy);
        sx = fmaf(v3, x3, sx); sy = fmaf(v3, y3, sy);
        qx = fmaf(v3 * x3, x3, qx); qy = fmaf(v3 * y3, y3, qy);
    }
    for (; e < end; ++e) {
        int2 c0 = ldnt(&pk[e]);
        uint u0 = Xb[(c0.x << 6) + lane];
        float v0 = __int_as_float(c0.y);
        float x0 = bfl(u0), y0 = bfh(u0);
        sx = fmaf(v0, x0, sx); sy = fmaf(v0, y0, sy);
        qx = fmaf(v0 * x0, x0, qx); qy = fmaf(v0 * y0, y0, qy);
    }
}

// both bilinear pairs in ONE launch: blockIdx.y selects (A,B,out). Same per-thread
// state as bp2 (VGPR ~20, occupancy preserved); both halves walk Pb's sorted
// column band simultaneously -> touches per L2 line double within a window.
__global__ __launch_bounds__(256) void spmm_bp2x2(
        const int* __restrict__ rp1, const int2* __restrict__ pk1,
        const int* __restrict__ rp2, const int2* __restrict__ pk2,
        const int* __restrict__ rp3, const int2* __restrict__ pk3,
        const int* __restrict__ rp4, const int2* __restrict__ pk4,
        const uint* __restrict__ Xb, uint* __restrict__ t1b, uint* __restrict__ t2b, int N) {
    int pair = blockIdx.y;
    const int* rpA = pair ? rp3 : rp1;
    const int2* pkA = pair ? pk3 : pk1;
    const int* rpB = pair ? rp4 : rp2;
    const int2* pkB = pair ? pk4 : pk2;
    uint* outb = pair ? t2b : t1b;
    int w = threadIdx.x >> 6, lane = threadIdx.x & 63;
    int stride = gridDim.x * 4;
    for (int row = blockIdx.x * 4 + w; row < N; row += stride) {
        float sax = 0.f, say = 0.f, qax = 0.f, qay = 0.f;
        float sbx = 0.f, sby = 0.f, qbx = 0.f, qby = 0.f;
        row_gather_bp(pkA, rpA[row], rpA[row + 1], Xb, lane, sax, say, qax, qay);
        row_gather_bp(pkB, rpB[row], rpB[row + 1], Xb, lane, sbx, sby, qbx, qby);
        float tx = 0.5f * ((sax * sax - qax) - (sbx * sbx - qbx));
        float ty = 0.5f * ((say * say - qay) - (sby * sby - qby));
        outb[((size_t)row << 6) + lane] = packbf2(tx, ty);
    }
}

__global__ __launch_bounds__(256) void spmm_out(const int* __restrict__ rp0,
        const int2* __restrict__ pk0, const int* __restrict__ rp5,
        const int2* __restrict__ pk5, const int* __restrict__ rp6,
        const int2* __restrict__ pk6, const uint* __restrict__ Pb,
        const uint* __restrict__ t1b, const uint* __restrict__ t2b,
        float* __restrict__ out, int N) {
    int w = threadIdx.x >> 6, lane = threadIdx.x & 63;
    int stride = gridDim.x * 4;
    for (int row = blockIdx.x * 4 + w; row < N; row += stride) {
        float a0x = 0.f, a0y = 0.f, a5x = 0.f, a5y = 0.f, a6x = 0.f, a6y = 0.f;
        row_gather_sum(pk0, rp0[row], rp0[row + 1], Pb,  lane, a0x, a0y);
        row_gather_sum(pk5, rp5[row], rp5[row + 1], t1b, lane, a5x, a5y);
        row_gather_sum(pk6, rp6[row], rp6[row + 1], t2b, lane, a6x, a6y);
        float rx = fmaxf(0.5f * a0x + 0.25f * a5x + 0.25f * a6x, 0.f);
        float ry = fmaxf(0.5f * a0y + 0.25f * a5y + 0.25f * a6y, 0.f);
        *(float2*)(out + ((size_t)row << 7) + (lane << 1)) = make_float2(rx, ry);
    }
}

// ---------------- launch ----------------

extern "C" void kernel_launch(void* const* d_in, const int* in_sizes, int n_in,
                              void* d_out, int out_size, void* d_ws, size_t ws_size,
                              hipStream_t stream) {
    (void)n_in; (void)out_size;
    const float* x   = (const float*)d_in[0];
    const float* Wa  = (const float*)d_in[1];
    const float* Wb  = (const float*)d_in[2];
    const float* w1  = (const float*)d_in[4];
    const float* b1  = (const float*)d_in[5];
    const float* w2  = (const float*)d_in[6];
    const int* rows  = (const int*)d_in[7];
    const int* cols  = (const int*)d_in[8];
    const float* vals = (const float*)d_in[9];
    float* out = (float*)d_out;

    const int N = in_sizes[0] / 256;
    const int E = in_sizes[7] / 7;
    const int NSB = (N + SBROWS - 1) >> SBSHIFT;
    const int nchunks = (E + CH - 1) / CH;

    auto layoutBytes = [&](int ns) -> size_t {
        size_t bts = 3 * (size_t)N * 64 * 4;
        bts += (size_t)ns * E * 8;
        size_t region = (size_t)N * 1024;
        if ((size_t)ns * E * 8 > region) region = (size_t)ns * E * 8;
        bts += region;
        bts += (size_t)ns * (N + 1) * 4;
        bts += 2 * (size_t)ns * NSB * (size_t)nchunks * 4;
        bts += (size_t)ns * NSB * 4;
        bts += (size_t)ns * (NSB + 1) * 4;
        return bts + 4096;
    };
    const int NSUP = (ws_size >= layoutBytes(7)) ? 7 : 4;

    uint* Pb  = (uint*)d_ws;
    uint* t1b = Pb + (size_t)N * 64;
    uint* t2b = t1b + (size_t)N * 64;
    int2* pk  = (int2*)(t2b + (size_t)N * 64);
    size_t regionFloats = (size_t)N * 256;
    if ((size_t)NSUP * E * 2 > regionFloats) regionFloats = (size_t)NSUP * E * 2;
    int2* stage2 = pk + (size_t)NSUP * E;
    float* AB    = (float*)stage2;
    int* rp      = (int*)((float*)stage2 + regionFloats);
    int* lenTab  = rp + (size_t)NSUP * (N + 1);
    int* segPos  = lenTab + (size_t)NSUP * NSB * nchunks;
    int* btot    = segPos + (size_t)NSUP * NSB * nchunks;
    int* bbase   = btot + (size_t)NSUP * NSB;

    dim3 b256(256);
    int sgrid = (N + 3) / 4;
    int pgrid = PGRID; if (pgrid > sgrid) pgrid = sgrid;
    int hgrid = pgrid / 2;          // co-residency: hgrid * 2 pairs = 2048 blocks
    int bgrid = (NSB + 255) / 256;

    gemm_kernel<<<(N + BM - 1) / BM, b256, 0, stream>>>(x, Wa, Wb, AB, N);
    attn_kernel<<<sgrid, b256, 0, stream>>>(AB, w1, b1, w2, Pb, N);

    auto build = [&](int4 mlo, int4 mhi, int nsup) {
        count_chunk<<<dim3(nchunks, nsup), b256, 0, stream>>>(rows, mlo, mhi, lenTab,
                                                              NSB, nchunks, E);
        btot_kernel<<<dim3(bgrid, nsup), b256, 0, stream>>>(lenTab, btot, NSB, nchunks);
        bucket_scanex<<<nsup, b256, 0, stream>>>(btot, bbase, NSB);
        pos_scan<<<dim3(NSB, nsup), dim3(64), 0, stream>>>(lenTab, bbase, segPos, NSB, nchunks);
        place_chunk<<<dim3(nchunks, nsup), b256, 0, stream>>>(rows, cols, vals, mlo, mhi,
                                                              segPos, stage2, NSB, nchunks, E);
        fill_bucket<<<dim3(NSB, nsup), b256, 0, stream>>>(stage2, bbase, rp, pk, NSB, N, E);
    };

    const size_t NP1 = (size_t)(N + 1);

    if (NSUP == 7) {
        // one build for all 7 supports: slots {1,3,2,4,0,5,6}
        build(make_int4(1, 3, 2, 4), make_int4(0, 5, 6, 6), 7);
        spmm_bp2x2<<<dim3(hgrid, 2), b256, 0, stream>>>(
            rp + 0 * NP1, pk + 0 * (size_t)E, rp + 1 * NP1, pk + 1 * (size_t)E,
            rp + 2 * NP1, pk + 2 * (size_t)E, rp + 3 * NP1, pk + 3 * (size_t)E,
            Pb, t1b, t2b, N);
        spmm_out<<<pgrid, b256, 0, stream>>>(rp + 4 * NP1, pk + 4 * (size_t)E,
                                             rp + 5 * NP1, pk + 5 * (size_t)E,
                                             rp + 6 * NP1, pk + 6 * (size_t)E,
                                             Pb, t1b, t2b, out, N);
    } else {
        // fallback: two build groups
        build(make_int4(1, 3, 2, 4), make_int4(0, 0, 0, 0), 4);
        spmm_bp2x2<<<dim3(hgrid, 2), b256, 0, stream>>>(
            rp + 0 * NP1, pk + 0 * (size_t)E, rp + 1 * NP1, pk + 1 * (size_t)E,
            rp + 2 * NP1, pk + 2 * (size_t)E, rp + 3 * NP1, pk + 3 * (size_t)E,
            Pb, t1b, t2b, N);
        build(make_int4(0, 5, 6, 6), make_int4(0, 0, 0, 0), 3);
        spmm_out<<<pgrid, b256, 0, stream>>>(rp + 0 * NP1, pk + 0 * (size_t)E,
                                             rp + 1 * NP1, pk + 1 * (size_t)E,
                                             rp + 2 * NP1, pk + 2 * (size_t)E,
                                             Pb, t1b, t2b, out, N);
    }
}

// Round 14
// 2108.994 us; speedup vs baseline: 1.1641x; 1.0230x over previous
//
#include <hip/hip_runtime.h>

typedef unsigned int uint;
typedef unsigned short ushort;

__device__ __forceinline__ float bfl(uint u){ return __uint_as_float(u << 16); }
__device__ __forceinline__ float bfh(uint u){ return __uint_as_float(u & 0xFFFF0000u); }
__device__ __forceinline__ uint f2bfbits(float f){
    uint b = __float_as_uint(f);
    return (b + 0x7FFFu + ((b >> 16) & 1u)) >> 16;
}
__device__ __forceinline__ uint packbf2(float a, float b){
    return f2bfbits(a) | (f2bfbits(b) << 16);
}
__device__ __forceinline__ int smap8(int4 lo, int4 hi, int s){
    int4 m = (s < 4) ? lo : hi;
    int k = s & 3;
    return (k == 0) ? m.x : (k == 1) ? m.y : (k == 2) ? m.z : m.w;
}
__device__ __forceinline__ int2 ldnt(const int2* p){
    long long v = __builtin_nontemporal_load((const long long*)p);
    int2 r; r.x = (int)(v & 0xFFFFFFFFll); r.y = (int)(v >> 32); return r;
}
// bijective XCD-contiguous chunk swizzle
__device__ __forceinline__ int xcd_swz(int bid, int n){
    int q = n >> 3, r = n & 7;
    int x = bid & 7, i = bid >> 3;
    return (x < r) ? (x * (q + 1) + i) : (r * (q + 1) + (x - r) * q + i);
}

#define CH 6144
#define SBSHIFT 7
#define SBROWS 128
#define HISTP 784
#define SBUF_CAP 5120
#define CACHE_PT 20
#define PGRID 2048

// ---------------- dense part ----------------

#define BM 64
#define BK 32
__global__ __launch_bounds__(256) void gemm_kernel(const float* __restrict__ x,
                                                   const float* __restrict__ Wa,
                                                   const float* __restrict__ Wb,
                                                   float* __restrict__ AB, int N) {
    __shared__ float xsT[BK][BM + 4];
    __shared__ float wsm[BK][256];
    int t = threadIdx.x;
    int rowbase = blockIdx.x * BM;
    int tx = t & 15, ty = t >> 4;
    float acc[4][16];
    #pragma unroll
    for (int i = 0; i < 4; i++)
        #pragma unroll
        for (int j = 0; j < 16; j++) acc[i][j] = 0.f;

    for (int k0 = 0; k0 < 256; k0 += BK) {
        {
            int r = t & 63;
            int koff = (t >> 6) * 8;
            int gr = rowbase + r; if (gr >= N) gr = N - 1;
            const float* src = x + (size_t)gr * 256 + k0 + koff;
            float4 u0 = *(const float4*)(src);
            float4 u1 = *(const float4*)(src + 4);
            xsT[koff + 0][r] = u0.x; xsT[koff + 1][r] = u0.y;
            xsT[koff + 2][r] = u0.z; xsT[koff + 3][r] = u0.w;
            xsT[koff + 4][r] = u1.x; xsT[koff + 5][r] = u1.y;
            xsT[koff + 6][r] = u1.z; xsT[koff + 7][r] = u1.w;
        }
        {
            #pragma unroll
            for (int i = 0; i < 8; i++) {
                int f = t + i * 256;
                int rr = f >> 6, c4 = f & 63;
                const float* src = (c4 < 32) ? &Wa[(size_t)(k0 + rr) * 128 + c4 * 4]
                                             : &Wb[(size_t)(k0 + rr) * 128 + (c4 - 32) * 4];
                *(float4*)&wsm[rr][c4 * 4] = *(const float4*)src;
            }
        }
        __syncthreads();
        #pragma unroll
        for (int kk = 0; kk < BK; ++kk) {
            float4 a = *(const float4*)&xsT[kk][ty * 4];
            float av[4] = {a.x, a.y, a.z, a.w};
            float bv[16];
            #pragma unroll
            for (int q = 0; q < 4; q++)
                *(float4*)&bv[q * 4] = *(const float4*)&wsm[kk][q * 64 + tx * 4];
            #pragma unroll
            for (int i = 0; i < 4; i++)
                #pragma unroll
                for (int j = 0; j < 16; j++)
                    acc[i][j] = fmaf(av[i], bv[j], acc[i][j]);
        }
        __syncthreads();
    }
    #pragma unroll
    for (int i = 0; i < 4; i++) {
        int gr = rowbase + ty * 4 + i;
        if (gr < N) {
            #pragma unroll
            for (int q = 0; q < 4; q++) {
                float4 o = {acc[i][q*4], acc[i][q*4+1], acc[i][q*4+2], acc[i][q*4+3]};
                *(float4*)&AB[(size_t)gr * 256 + q * 64 + tx * 4] = o;
            }
        }
    }
}

// attention: Pb[n] packed bf16 [N][128]
__global__ __launch_bounds__(256) void attn_kernel(const float* __restrict__ AB,
        const float* __restrict__ w1, const float* __restrict__ b1,
        const float* __restrict__ w2, uint* __restrict__ Pb, int N) {
    __shared__ float w1s[128 * 32];
    __shared__ float b1s[32], w2s[32];
    __shared__ float aS[4][128], alS[4][128];
    int t = threadIdx.x;
    #pragma unroll
    for (int i = 0; i < 16; i++) w1s[t + i * 256] = w1[t + i * 256];
    if (t < 32) { b1s[t] = b1[t]; w2s[t] = w2[t]; }

    int w = t >> 6, lane = t & 63;
    int node = blockIdx.x * 4 + w;
    bool active = node < N;
    int nclamp = active ? node : (N - 1);
    float2 a = *(const float2*)(AB + (size_t)nclamp * 256 + lane * 2);
    float2 b = *(const float2*)(AB + (size_t)nclamp * 256 + 128 + lane * 2);
    float2 al;
    al.x = a.x + 0.5f * (a.x * a.x - a.x * b.x);
    al.y = a.y + 0.5f * (a.y * a.y - a.y * b.y);
    aS[w][lane * 2] = a.x;   aS[w][lane * 2 + 1] = a.y;
    alS[w][lane * 2] = al.x; alS[w][lane * 2 + 1] = al.y;
    __syncthreads();

    int j = lane & 31;
    const float* src = (lane < 32) ? aS[w] : alS[w];
    float acc = b1s[j];
    #pragma unroll 8
    for (int d = 0; d < 128; ++d) acc = fmaf(src[d], w1s[d * 32 + j], acc);
    float h = tanhf(acc);
    float prod = h * w2s[j];
    #pragma unroll
    for (int off = 1; off < 32; off <<= 1) prod += __shfl_xor(prod, off);
    float eo = __shfl_xor(prod, 32);
    float e0 = (lane < 32) ? prod : eo;
    float e1 = (lane < 32) ? eo : prod;
    float m = fmaxf(e0, e1);
    float p0 = expf(e0 - m), p1 = expf(e1 - m);
    float inv = 1.0f / (p0 + p1);
    float at0 = p0 * inv, at1 = p1 * inv;
    if (active) {
        float px = at0 * a.x + at1 * al.x;
        float py = at0 * a.y + at1 * al.y;
        Pb[(size_t)node * 64 + lane] = packbf2(px, py);
    }
}

// ---------------- CSR build (bucket-major reorder, zero global atomics) ----------------

__device__ __forceinline__ void block_scan1024(int* a, int t, int* wsum) {
    int lane = t & 63, wid = t >> 6;
    int c0 = a[t * 4], c1 = a[t * 4 + 1], c2 = a[t * 4 + 2], c3 = a[t * 4 + 3];
    int tsum = c0 + c1 + c2 + c3, incl = tsum;
    #pragma unroll
    for (int off = 1; off < 64; off <<= 1) {
        int y = __shfl_up(incl, off);
        if (lane >= off) incl += y;
    }
    if (lane == 63) wsum[wid] = incl;
    __syncthreads();
    int wb = 0;
    #pragma unroll
    for (int w = 0; w < 4; w++) if (w < wid) wb += wsum[w];
    int excl = wb + incl - tsum;
    a[t * 4] = excl; a[t * 4 + 1] = excl + c0;
    a[t * 4 + 2] = excl + c0 + c1; a[t * 4 + 3] = excl + c0 + c1 + c2;
    __syncthreads();
}

// 1: per-(chunk,bucket) counts AND chunk-local exclusive offsets, packed off|len<<16.
// place_chunk then skips its own histogram+scan entirely.
__global__ __launch_bounds__(256) void count_chunk(const int* __restrict__ rows,
        int4 mlo, int4 mhi, int* __restrict__ olTab, int NSB, int nchunks, int E) {
    __shared__ int hist[1024];
    __shared__ int wsum[4];
    int c = xcd_swz(blockIdx.x, nchunks), s = blockIdx.y, t = threadIdx.x;
    size_t sb = (size_t)smap8(mlo, mhi, s) * E;
    int e0 = c * CH, e1 = e0 + CH; if (e1 > E) e1 = E;
    #pragma unroll
    for (int k = 0; k < 4; k++) hist[t + k * 256] = 0;
    __syncthreads();
    for (int e = e0 + t; e < e1; e += 256)
        atomicAdd(&hist[(uint)rows[sb + e] >> SBSHIFT], 1);
    __syncthreads();
    int idx = t * 4;
    int l0 = hist[idx], l1 = hist[idx + 1], l2 = hist[idx + 2], l3 = hist[idx + 3];
    block_scan1024(hist, t, wsum);   // hist -> exclusive offsets
    int lens[4] = {l0, l1, l2, l3};
    #pragma unroll
    for (int k = 0; k < 4; k++) {
        int b = idx + k;
        if (b < NSB)
            olTab[((size_t)s * NSB + b) * nchunks + c] = hist[b] | (lens[k] << 16);
    }
}

// 1b: bucket totals by contiguous row-sum of olTab's len field
__global__ __launch_bounds__(256) void btot_kernel(const int* __restrict__ olTab,
        int* __restrict__ btot, int NSB, int nchunks) {
    int s = blockIdx.y;
    int b = blockIdx.x * 256 + threadIdx.x;
    if (b >= NSB) return;
    const int* lt = olTab + ((size_t)s * NSB + b) * nchunks;
    int a0 = 0, a1 = 0, a2 = 0, a3 = 0;
    int c = 0;
    for (; c + 4 <= nchunks; c += 4) {
        a0 += (int)(((uint)lt[c])     >> 16); a1 += (int)(((uint)lt[c + 1]) >> 16);
        a2 += (int)(((uint)lt[c + 2]) >> 16); a3 += (int)(((uint)lt[c + 3]) >> 16);
    }
    for (; c < nchunks; ++c) a0 += (int)(((uint)lt[c]) >> 16);
    btot[s * NSB + b] = a0 + a1 + a2 + a3;
}

__global__ __launch_bounds__(256) void bucket_scanex(const int* __restrict__ btot,
        int* __restrict__ bbase, int NSB) {
    __shared__ int a[1024];
    __shared__ int wsum[4];
    int s = blockIdx.x, t = threadIdx.x;
    #pragma unroll
    for (int k = 0; k < 4; k++) {
        int i = t + k * 256;
        a[i] = (i < NSB) ? btot[s * NSB + i] : 0;
    }
    __syncthreads();
    block_scan1024(a, t, wsum);
    #pragma unroll
    for (int k = 0; k < 4; k++) {
        int i = t + k * 256;
        if (i <= NSB) bbase[s * (NSB + 1) + i] = a[i];
    }
}

__global__ __launch_bounds__(64) void pos_scan(const int* __restrict__ olTab,
        const int* __restrict__ bbase, int* __restrict__ segPos, int NSB, int nchunks) {
    int b = blockIdx.x, s = blockIdx.y, lane = threadIdx.x;
    const int* lt = olTab + ((size_t)s * NSB + b) * nchunks;
    int* sp = segPos + ((size_t)s * NSB + b) * nchunks;
    int run = bbase[s * (NSB + 1) + b];
    for (int c0 = 0; c0 < nchunks; c0 += 64) {
        int c = c0 + lane;
        int v = (c < nchunks) ? (int)(((uint)lt[c]) >> 16) : 0;
        int incl = v;
        #pragma unroll
        for (int off = 1; off < 64; off <<= 1) {
            int y = __shfl_up(incl, off);
            if (lane >= off) incl += y;
        }
        if (c < nchunks) sp[c] = run + incl - v;
        run += __shfl(incl, 63);
    }
}

// 4: placement only (offsets from olTab) -> bucket-major stage2 at precomputed slots
__global__ __launch_bounds__(256) void place_chunk(const int* __restrict__ rows,
        const int* __restrict__ cols, const float* __restrict__ vals,
        int4 mlo, int4 mhi, const int* __restrict__ olTab, const int* __restrict__ segPos,
        int2* __restrict__ stage2, int NSB, int nchunks, int E) {
    __shared__ int2 sbuf[CH];
    __shared__ ushort bmap[CH];
    __shared__ int cur[HISTP];
    __shared__ int off[HISTP];
    __shared__ int spos[HISTP];
    int c = xcd_swz(blockIdx.x, nchunks), s = blockIdx.y, t = threadIdx.x;
    size_t sb = (size_t)smap8(mlo, mhi, s) * E;
    int e0 = c * CH, e1 = e0 + CH; if (e1 > E) e1 = E;
    int csz = e1 - e0;
    for (int b = t; b < NSB; b += 256) {
        size_t tb = ((size_t)s * NSB + b) * nchunks + c;
        int p = olTab[tb];
        int o = p & 0xFFFF;
        cur[b] = o; off[b] = o;
        spos[b] = segPos[tb];
    }
    __syncthreads();
    for (int e = e0 + t; e < e1; e += 256) {
        int r = rows[sb + e];
        int b = (uint)r >> SBSHIFT;
        int pos = atomicAdd(&cur[b], 1);
        uint cw = (uint)cols[sb + e] | ((uint)(r & (SBROWS - 1)) << 20);
        sbuf[pos] = make_int2((int)cw, __float_as_int(vals[sb + e]));
        bmap[pos] = (ushort)b;
    }
    __syncthreads();
    int2* dst = stage2 + (size_t)s * E;
    for (int i = t; i < csz; i += 256) {
        int b = bmap[i];
        dst[spos[b] + (i - off[b])] = sbuf[i];
    }
}

__global__ __launch_bounds__(256) void fill_bucket(const int2* __restrict__ stage2,
        const int* __restrict__ bbase, int* __restrict__ rp, int2* __restrict__ pk,
        int NSB, int N, int E) {
    __shared__ int2 sbuf[SBUF_CAP];
    __shared__ int cur[128];
    __shared__ int loc[132];
    __shared__ int wsum2[2];
    int b = blockIdx.x, s = blockIdx.y, t = threadIdx.x;
    int lane = t & 63, wid = t >> 6;
    int rowbase = b << SBSHIFT;
    int nrows = N - rowbase; if (nrows > SBROWS) nrows = SBROWS;
    size_t sb = (size_t)s * E;
    int beg = bbase[s * (NSB + 1) + b];
    int end = bbase[s * (NSB + 1) + b + 1];
    int tot = end - beg;
    if (t < 128) cur[t] = 0;
    __syncthreads();
    int2 myE[CACHE_PT];
    #pragma unroll
    for (int k = 0; k < CACHE_PT; k++) {
        int idx = t + k * 256;
        if (idx < tot) {
            int2 u = stage2[sb + beg + idx];
            myE[k] = u;
            atomicAdd(&cur[((uint)u.x) >> 20], 1);
        }
    }
    for (int idx = t + CACHE_PT * 256; idx < tot; idx += 256) {
        int2 u = stage2[sb + beg + idx];
        atomicAdd(&cur[((uint)u.x) >> 20], 1);
    }
    __syncthreads();
    int v = 0, incl = 0;
    if (t < 128) {
        v = cur[t]; incl = v;
        #pragma unroll
        for (int off = 1; off < 64; off <<= 1) {
            int y = __shfl_up(incl, off);
            if (lane >= off) incl += y;
        }
        if (lane == 63) wsum2[wid] = incl;
    }
    __syncthreads();
    if (t < 128) {
        int excl = incl - v + ((wid == 1) ? wsum2[0] : 0);
        loc[t] = excl; cur[t] = excl;
        if (t < nrows) rp[(size_t)s * (N + 1) + rowbase + t] = beg + excl;
    }
    if (t == 0) loc[128] = tot;
    if (b == 0 && t == 0) rp[(size_t)s * (N + 1) + N] = E;
    __syncthreads();
    #pragma unroll
    for (int k = 0; k < CACHE_PT; k++) {
        int idx = t + k * 256;
        if (idx < tot) {
            int2 u = myE[k];
            int lr = ((uint)u.x) >> 20;
            int pos = atomicAdd(&cur[lr], 1);
            int2 w = make_int2(u.x & 0xFFFFF, u.y);
            if (pos < SBUF_CAP) sbuf[pos] = w; else pk[sb + beg + pos] = w;
        }
    }
    for (int idx = t + CACHE_PT * 256; idx < tot; idx += 256) {
        int2 u = stage2[sb + beg + idx];
        int lr = ((uint)u.x) >> 20;
        int pos = atomicAdd(&cur[lr], 1);
        int2 w = make_int2(u.x & 0xFFFFF, u.y);
        if (pos < SBUF_CAP) sbuf[pos] = w; else pk[sb + beg + pos] = w;
    }
    __syncthreads();
    for (int r = wid; r < nrows; r += 4) {
        int rb = loc[r], re = loc[r + 1];
        int deg = re - rb;
        if (deg < 2 || deg > 64 || re > SBUF_CAP) continue;
        int key = 0x7FFFFFFF, val = 0;
        if (lane < deg) { int2 u = sbuf[rb + lane]; key = u.x; val = u.y; }
        #pragma unroll
        for (int k = 2; k <= 64; k <<= 1) {
            #pragma unroll
            for (int j = k >> 1; j > 0; j >>= 1) {
                int okey = __shfl_xor(key, j);
                int oval = __shfl_xor(val, j);
                bool up = ((lane & k) == 0);
                bool lower = ((lane & j) == 0);
                bool keepmin = (lower == up);
                bool take = keepmin ? (okey < key) : (okey > key);
                if (take) { key = okey; val = oval; }
            }
        }
        if (lane < deg) sbuf[rb + lane] = make_int2(key, val);
    }
    __syncthreads();
    int lim = (tot < SBUF_CAP) ? tot : SBUF_CAP;
    for (int i = t; i < lim; i += 256)
        __builtin_nontemporal_store(*(const long long*)&sbuf[i], (long long*)&pk[sb + beg + i]);
}

// ---------------- fused SpMM kernels (persistent, sorted-walk, MLP=4) ----------------

__device__ __forceinline__ void row_gather_sum(const int2* __restrict__ pk,
        int e, int end, const uint* __restrict__ Xb, int lane,
        float& ax, float& ay) {
    for (; e + 4 <= end; e += 4) {
        int2 c0 = ldnt(&pk[e]);     int2 c1 = ldnt(&pk[e + 1]);
        int2 c2 = ldnt(&pk[e + 2]); int2 c3 = ldnt(&pk[e + 3]);
        uint u0 = Xb[(c0.x << 6) + lane]; uint u1 = Xb[(c1.x << 6) + lane];
        uint u2 = Xb[(c2.x << 6) + lane]; uint u3 = Xb[(c3.x << 6) + lane];
        float v0 = __int_as_float(c0.y), v1 = __int_as_float(c1.y);
        float v2 = __int_as_float(c2.y), v3 = __int_as_float(c3.y);
        ax = fmaf(v0, bfl(u0), ax); ay = fmaf(v0, bfh(u0), ay);
        ax = fmaf(v1, bfl(u1), ax); ay = fmaf(v1, bfh(u1), ay);
        ax = fmaf(v2, bfl(u2), ax); ay = fmaf(v2, bfh(u2), ay);
        ax = fmaf(v3, bfl(u3), ax); ay = fmaf(v3, bfh(u3), ay);
    }
    for (; e < end; ++e) {
        int2 c0 = ldnt(&pk[e]);
        uint u0 = Xb[(c0.x << 6) + lane];
        float v0 = __int_as_float(c0.y);
        ax = fmaf(v0, bfl(u0), ax); ay = fmaf(v0, bfh(u0), ay);
    }
}

__device__ __forceinline__ void row_gather_bp(const int2* __restrict__ pk,
        int e, int end, const uint* __restrict__ Xb, int lane,
        float& sx, float& sy, float& qx, float& qy) {
    for (; e + 4 <= end; e += 4) {
        int2 c0 = ldnt(&pk[e]);     int2 c1 = ldnt(&pk[e + 1]);
        int2 c2 = ldnt(&pk[e + 2]); int2 c3 = ldnt(&pk[e + 3]);
        uint u0 = Xb[(c0.x << 6) + lane]; uint u1 = Xb[(c1.x << 6) + lane];
        uint u2 = Xb[(c2.x << 6) + lane]; uint u3 = Xb[(c3.x << 6) + lane];
        float v0 = __int_as_float(c0.y), v1 = __int_as_float(c1.y);
        float v2 = __int_as_float(c2.y), v3 = __int_as_float(c3.y);
        float x0 = bfl(u0), y0 = bfh(u0), x1 = bfl(u1), y1 = bfh(u1);
        float x2 = bfl(u2), y2 = bfh(u2), x3 = bfl(u3), y3 = bfh(u3);
        sx = fmaf(v0, x0, sx); sy = fmaf(v0, y0, sy);
        qx = fmaf(v0 * x0, x0, qx); qy = fmaf(v0 * y0, y0, qy);
        sx = fmaf(v1, x1, sx); sy = fmaf(v1, y1, sy);
        qx = fmaf(v1 * x1, x1, qx); qy = fmaf(v1 * y1, y1, qy);
        sx = fmaf(v2, x2, sx); sy = fmaf(v2, y2, sy);
        qx = fmaf(v2 * x2, x2, qx); qy = fmaf(v2 * y2, y2, qy);
        sx = fmaf(v3, x3, sx); sy = fmaf(v3, y3, sy);
        qx = fmaf(v3 * x3, x3, qx); qy = fmaf(v3 * y3, y3, qy);
    }
    for (; e < end; ++e) {
        int2 c0 = ldnt(&pk[e]);
        uint u0 = Xb[(c0.x << 6) + lane];
        float v0 = __int_as_float(c0.y);
        float x0 = bfl(u0), y0 = bfh(u0);
        sx = fmaf(v0, x0, sx); sy = fmaf(v0, y0, sy);
        qx = fmaf(v0 * x0, x0, qx); qy = fmaf(v0 * y0, y0, qy);
    }
}

__global__ __launch_bounds__(256) void spmm_bp2x2(
        const int* __restrict__ rp1, const int2* __restrict__ pk1,
        const int* __restrict__ rp2, const int2* __restrict__ pk2,
        const int* __restrict__ rp3, const int2* __restrict__ pk3,
        const int* __restrict__ rp4, const int2* __restrict__ pk4,
        const uint* __restrict__ Xb, uint* __restrict__ t1b, uint* __restrict__ t2b, int N) {
    int pair = blockIdx.y;
    const int* rpA = pair ? rp3 : rp1;
    const int2* pkA = pair ? pk3 : pk1;
    const int* rpB = pair ? rp4 : rp2;
    const int2* pkB = pair ? pk4 : pk2;
    uint* outb = pair ? t2b : t1b;
    int w = threadIdx.x >> 6, lane = threadIdx.x & 63;
    int stride = gridDim.x * 4;
    for (int row = blockIdx.x * 4 + w; row < N; row += stride) {
        float sax = 0.f, say = 0.f, qax = 0.f, qay = 0.f;
        float sbx = 0.f, sby = 0.f, qbx = 0.f, qby = 0.f;
        row_gather_bp(pkA, rpA[row], rpA[row + 1], Xb, lane, sax, say, qax, qay);
        row_gather_bp(pkB, rpB[row], rpB[row + 1], Xb, lane, sbx, sby, qbx, qby);
        float tx = 0.5f * ((sax * sax - qax) - (sbx * sbx - qbx));
        float ty = 0.5f * ((say * say - qay) - (sby * sby - qby));
        outb[((size_t)row << 6) + lane] = packbf2(tx, ty);
    }
}

__global__ __launch_bounds__(256) void spmm_out(const int* __restrict__ rp0,
        const int2* __restrict__ pk0, const int* __restrict__ rp5,
        const int2* __restrict__ pk5, const int* __restrict__ rp6,
        const int2* __restrict__ pk6, const uint* __restrict__ Pb,
        const uint* __restrict__ t1b, const uint* __restrict__ t2b,
        float* __restrict__ out, int N) {
    int w = threadIdx.x >> 6, lane = threadIdx.x & 63;
    int stride = gridDim.x * 4;
    for (int row = blockIdx.x * 4 + w; row < N; row += stride) {
        float a0x = 0.f, a0y = 0.f, a5x = 0.f, a5y = 0.f, a6x = 0.f, a6y = 0.f;
        row_gather_sum(pk0, rp0[row], rp0[row + 1], Pb,  lane, a0x, a0y);
        row_gather_sum(pk5, rp5[row], rp5[row + 1], t1b, lane, a5x, a5y);
        row_gather_sum(pk6, rp6[row], rp6[row + 1], t2b, lane, a6x, a6y);
        float rx = fmaxf(0.5f * a0x + 0.25f * a5x + 0.25f * a6x, 0.f);
        float ry = fmaxf(0.5f * a0y + 0.25f * a5y + 0.25f * a6y, 0.f);
        *(float2*)(out + ((size_t)row << 7) + (lane << 1)) = make_float2(rx, ry);
    }
}

// ---------------- launch ----------------

extern "C" void kernel_launch(void* const* d_in, const int* in_sizes, int n_in,
                              void* d_out, int out_size, void* d_ws, size_t ws_size,
                              hipStream_t stream) {
    (void)n_in; (void)out_size;
    const float* x   = (const float*)d_in[0];
    const float* Wa  = (const float*)d_in[1];
    const float* Wb  = (const float*)d_in[2];
    const float* w1  = (const float*)d_in[4];
    const float* b1  = (const float*)d_in[5];
    const float* w2  = (const float*)d_in[6];
    const int* rows  = (const int*)d_in[7];
    const int* cols  = (const int*)d_in[8];
    const float* vals = (const float*)d_in[9];
    float* out = (float*)d_out;

    const int N = in_sizes[0] / 256;
    const int E = in_sizes[7] / 7;
    const int NSB = (N + SBROWS - 1) >> SBSHIFT;
    const int nchunks = (E + CH - 1) / CH;

    auto layoutBytes = [&](int ns) -> size_t {
        size_t bts = 3 * (size_t)N * 64 * 4;
        bts += (size_t)ns * E * 8;
        size_t region = (size_t)N * 1024;
        if ((size_t)ns * E * 8 > region) region = (size_t)ns * E * 8;
        bts += region;
        bts += (size_t)ns * (N + 1) * 4;
        bts += 2 * (size_t)ns * NSB * (size_t)nchunks * 4;
        bts += (size_t)ns * NSB * 4;
        bts += (size_t)ns * (NSB + 1) * 4;
        return bts + 4096;
    };
    const int NSUP = (ws_size >= layoutBytes(7)) ? 7 : 4;

    uint* Pb  = (uint*)d_ws;
    uint* t1b = Pb + (size_t)N * 64;
    uint* t2b = t1b + (size_t)N * 64;
    int2* pk  = (int2*)(t2b + (size_t)N * 64);
    size_t regionFloats = (size_t)N * 256;
    if ((size_t)NSUP * E * 2 > regionFloats) regionFloats = (size_t)NSUP * E * 2;
    int2* stage2 = pk + (size_t)NSUP * E;
    float* AB    = (float*)stage2;
    int* rp      = (int*)((float*)stage2 + regionFloats);
    int* olTab   = rp + (size_t)NSUP * (N + 1);
    int* segPos  = olTab + (size_t)NSUP * NSB * nchunks;
    int* btot    = segPos + (size_t)NSUP * NSB * nchunks;
    int* bbase   = btot + (size_t)NSUP * NSB;

    dim3 b256(256);
    int sgrid = (N + 3) / 4;
    int pgrid = PGRID; if (pgrid > sgrid) pgrid = sgrid;
    int hgrid = pgrid / 2;
    int bgrid = (NSB + 255) / 256;

    gemm_kernel<<<(N + BM - 1) / BM, b256, 0, stream>>>(x, Wa, Wb, AB, N);
    attn_kernel<<<sgrid, b256, 0, stream>>>(AB, w1, b1, w2, Pb, N);

    auto build = [&](int4 mlo, int4 mhi, int nsup) {
        count_chunk<<<dim3(nchunks, nsup), b256, 0, stream>>>(rows, mlo, mhi, olTab,
                                                              NSB, nchunks, E);
        btot_kernel<<<dim3(bgrid, nsup), b256, 0, stream>>>(olTab, btot, NSB, nchunks);
        bucket_scanex<<<nsup, b256, 0, stream>>>(btot, bbase, NSB);
        pos_scan<<<dim3(NSB, nsup), dim3(64), 0, stream>>>(olTab, bbase, segPos, NSB, nchunks);
        place_chunk<<<dim3(nchunks, nsup), b256, 0, stream>>>(rows, cols, vals, mlo, mhi,
                                                              olTab, segPos, stage2, NSB, nchunks, E);
        fill_bucket<<<dim3(NSB, nsup), b256, 0, stream>>>(stage2, bbase, rp, pk, NSB, N, E);
    };

    const size_t NP1 = (size_t)(N + 1);

    if (NSUP == 7) {
        build(make_int4(1, 3, 2, 4), make_int4(0, 5, 6, 6), 7);
        spmm_bp2x2<<<dim3(hgrid, 2), b256, 0, stream>>>(
            rp + 0 * NP1, pk + 0 * (size_t)E, rp + 1 * NP1, pk + 1 * (size_t)E,
            rp + 2 * NP1, pk + 2 * (size_t)E, rp + 3 * NP1, pk + 3 * (size_t)E,
            Pb, t1b, t2b, N);
        spmm_out<<<pgrid, b256, 0, stream>>>(rp + 4 * NP1, pk + 4 * (size_t)E,
                                             rp + 5 * NP1, pk + 5 * (size_t)E,
                                             rp + 6 * NP1, pk + 6 * (size_t)E,
                                             Pb, t1b, t2b, out, N);
    } else {
        build(make_int4(1, 3, 2, 4), make_int4(0, 0, 0, 0), 4);
        spmm_bp2x2<<<dim3(hgrid, 2), b256, 0, stream>>>(
            rp + 0 * NP1, pk + 0 * (size_t)E, rp + 1 * NP1, pk + 1 * (size_t)E,
            rp + 2 * NP1, pk + 2 * (size_t)E, rp + 3 * NP1, pk + 3 * (size_t)E,
            Pb, t1b, t2b, N);
        build(make_int4(0, 5, 6, 6), make_int4(0, 0, 0, 0), 3);
        spmm_out<<<pgrid, b256, 0, stream>>>(rp + 0 * NP1, pk + 0 * (size_t)E,
                                             rp + 1 * NP1, pk + 1 * (size_t)E,
                                             rp + 2 * NP1, pk + 2 * (size_t)E,
                                             Pb, t1b, t2b, out, N);
    }
}